// Round 1
// baseline (1446.654 us; speedup 1.0000x reference)
//
#include <hip/hip_runtime.h>
#include <math.h>

// Problem constants
constexpr int B    = 2;
constexpr int C    = 64;    // input channels
constexpr int H    = 224;
constexpr int W    = 224;
constexpr int K2   = 9;     // 3x3
constexpr int OCO  = 18;    // offset channels (2*K2)
constexpr int OM   = 27;    // offset + mask channels
constexpr int COUT = 64;
constexpr int HW   = H * W;         // 50176
constexpr int NPIX = B * HW;        // 100352
constexpr int CK   = C * K2;        // 576

// ---------------------------------------------------------------------------
// Kernel T1: transpose x from NCHW -> NHWC (xt[pix][c]) via LDS tiles
// ---------------------------------------------------------------------------
__global__ __launch_bounds__(256) void k_transpose(const float* __restrict__ x,
                                                   float* __restrict__ xt) {
    __shared__ float tile[32][33];
    const int b   = blockIdx.z;
    const int hw0 = blockIdx.x * 32;
    const int c0  = blockIdx.y * 32;
    const int tx  = threadIdx.x;   // 0..31
    const int ty  = threadIdx.y;   // 0..7
    const float* xb  = x  + (size_t)b * C * HW;
    float*       xtb = xt + (size_t)b * HW * C;
#pragma unroll
    for (int j = 0; j < 4; ++j) {
        int c = c0 + ty + j * 8;
        tile[ty + j * 8][tx] = xb[(size_t)c * HW + hw0 + tx];
    }
    __syncthreads();
#pragma unroll
    for (int j = 0; j < 4; ++j) {
        int hw = hw0 + ty + j * 8;
        xtb[(size_t)hw * C + c0 + tx] = tile[tx][ty + j * 8];
    }
}

// ---------------------------------------------------------------------------
// Kernel T2: wt[(c*9+k)*64 + o] = w_deform[o][c][k]
// ---------------------------------------------------------------------------
__global__ void k_wt(const float* __restrict__ wd, float* __restrict__ wt) {
    int i = blockIdx.x * 256 + threadIdx.x;
    if (i >= CK * COUT) return;
    int o  = i & 63;
    int ck = i >> 6;          // c*9 + k
    int c  = ck / 9;
    int k  = ck % 9;
    wt[i] = wd[((size_t)o * C + c) * 9 + k];
}

// ---------------------------------------------------------------------------
// Kernel C: offset + mask 3x3 conv from NCHW x.
// One wave handles 64 consecutive pixels for one output channel (wave-uniform
// oc -> weight loads are scalar). grid = (NPIX/64, 7), block = 256 (4 waves).
// Output layout: offmask[pix][27] (0..17 raw offsets, 18..26 sigmoid mask).
// ---------------------------------------------------------------------------
__global__ __launch_bounds__(256) void k_convom(const float* __restrict__ x,
                                                const float* __restrict__ w_off,
                                                const float* __restrict__ b_off,
                                                const float* __restrict__ w_msk,
                                                const float* __restrict__ b_msk,
                                                float* __restrict__ offmask) {
    const int lane = threadIdx.x & 63;
    const int oc   = blockIdx.y * 4 + (threadIdx.x >> 6);
    if (oc >= OM) return;
    const int pix = blockIdx.x * 64 + lane;
    const int b   = pix / HW;
    const int hw  = pix % HW;
    const int ho  = hw / W;
    const int wo  = hw % W;

    const float* wp   = (oc < OCO) ? (w_off + (size_t)oc * C * 9)
                                   : (w_msk + (size_t)(oc - OCO) * C * 9);
    float acc = (oc < OCO) ? b_off[oc] : b_msk[oc - OCO];

    const float* xb = x + (size_t)b * C * HW;
    for (int c = 0; c < C; ++c) {
        const float* xc = xb + (size_t)c * HW;
        const float* wc = wp + c * 9;
#pragma unroll
        for (int ky = 0; ky < 3; ++ky) {
            int y = ho + ky - 1;
            if (y < 0 || y >= H) continue;
#pragma unroll
            for (int kx = 0; kx < 3; ++kx) {
                int xx = wo + kx - 1;
                if (xx < 0 || xx >= W) continue;
                acc += xc[y * W + xx] * wc[ky * 3 + kx];
            }
        }
    }
    if (oc >= OCO) acc = 1.0f / (1.0f + __expf(-acc));
    offmask[(size_t)pix * OM + oc] = acc;
}

// ---------------------------------------------------------------------------
// Kernel D: deformable gather + per-pixel [64 x 576] contraction.
// 16 pixels per block, 256 threads.
//  Phase 1: lanes = channels; bilinear gather from NHWC xt -> LDS val.
//  Phase 2: lanes = out channels; 4 pixels per thread, float4 LDS broadcast.
// val layout: [(c*9+k)][p] with p-stride 20 floats (keeps 16B alignment).
// ---------------------------------------------------------------------------
constexpr int PPB  = 16;
constexpr int VSTR = 20;

__global__ __launch_bounds__(256) void k_deform(const float* __restrict__ xt,
                                                const float* __restrict__ offmask,
                                                const float* __restrict__ wt,
                                                float* __restrict__ out) {
    __shared__ __align__(16) float val[CK * VSTR];   // 576*20*4 = 46080 B
    const int tid  = threadIdx.x;
    const int pix0 = blockIdx.x * PPB;

    // ---- Phase 1: gather ----
    {
        const int c  = tid & 63;
        const int pl = tid >> 6;          // 0..3
        for (int po = 0; po < 4; ++po) {
            const int p   = po * 4 + pl;
            const int pix = pix0 + p;
            const int b   = pix / HW;
            const int hw  = pix % HW;
            const int ho  = hw / W;
            const int wo  = hw % W;
            const float* om = offmask + (size_t)pix * OM;
            const float* xb = xt + (size_t)b * HW * C;
#pragma unroll
            for (int k = 0; k < K2; ++k) {
                const float dy = om[2 * k];
                const float dx = om[2 * k + 1];
                const float m  = om[18 + k];
                const float py = dy + (float)(ho - 1 + k / 3);
                const float px = dx + (float)(wo - 1 + k % 3);
                const float fy = floorf(py);
                const float fx = floorf(px);
                const int   y0 = (int)fy;
                const int   x0 = (int)fx;
                const float wy1 = py - fy, wx1 = px - fx;
                const float wy0 = 1.0f - wy1, wx0 = 1.0f - wx1;
                float s = 0.0f;
                if (y0 >= 0 && y0 < H) {
                    if (x0 >= 0 && x0 < W)
                        s += (wy0 * wx0) * xb[((size_t)y0 * W + x0) * C + c];
                    if (x0 + 1 >= 0 && x0 + 1 < W)
                        s += (wy0 * wx1) * xb[((size_t)y0 * W + x0 + 1) * C + c];
                }
                if (y0 + 1 >= 0 && y0 + 1 < H) {
                    if (x0 >= 0 && x0 < W)
                        s += (wy1 * wx0) * xb[((size_t)(y0 + 1) * W + x0) * C + c];
                    if (x0 + 1 >= 0 && x0 + 1 < W)
                        s += (wy1 * wx1) * xb[((size_t)(y0 + 1) * W + x0 + 1) * C + c];
                }
                val[(c * 9 + k) * VSTR + p] = m * s;
            }
        }
    }
    __syncthreads();

    // ---- Phase 2: out[o][p] = sum_ck wt[ck][o] * val[ck][p] ----
    {
        const int o  = tid & 63;
        const int pg = tid >> 6;          // 0..3 -> pixels pg*4..pg*4+3
        float acc0 = 0.f, acc1 = 0.f, acc2 = 0.f, acc3 = 0.f;
        const float* wpo = wt + o;
#pragma unroll 4
        for (int ck = 0; ck < CK; ++ck) {
            const float  w = wpo[(size_t)ck * 64];
            const float4 v = *reinterpret_cast<const float4*>(&val[ck * VSTR + pg * 4]);
            acc0 = fmaf(w, v.x, acc0);
            acc1 = fmaf(w, v.y, acc1);
            acc2 = fmaf(w, v.z, acc2);
            acc3 = fmaf(w, v.w, acc3);
        }
        const int pix = pix0 + pg * 4;
        const int b   = pix / HW;
        const int hw  = pix % HW;         // pix..pix+3 stay in one row (16|HW)
        float4 r = make_float4(acc0, acc1, acc2, acc3);
        *reinterpret_cast<float4*>(&out[((size_t)b * COUT + o) * HW + hw]) = r;
    }
}

// ---------------------------------------------------------------------------
extern "C" void kernel_launch(void* const* d_in, const int* in_sizes, int n_in,
                              void* d_out, int out_size, void* d_ws, size_t ws_size,
                              hipStream_t stream) {
    const float* x     = (const float*)d_in[0];
    const float* w_off = (const float*)d_in[1];
    const float* b_off = (const float*)d_in[2];
    const float* w_msk = (const float*)d_in[3];
    const float* b_msk = (const float*)d_in[4];
    const float* w_def = (const float*)d_in[5];
    float* out = (float*)d_out;

    float* ws      = (float*)d_ws;
    float* xt      = ws;                          // NPIX*C
    float* offmask = xt + (size_t)NPIX * C;       // NPIX*27
    float* wt      = offmask + (size_t)NPIX * OM; // 576*64

    k_transpose<<<dim3(HW / 32, C / 32, B), dim3(32, 8), 0, stream>>>(x, xt);
    k_wt<<<(CK * COUT + 255) / 256, 256, 0, stream>>>(w_def, wt);
    k_convom<<<dim3(NPIX / 64, 7), dim3(256), 0, stream>>>(x, w_off, b_off,
                                                           w_msk, b_msk, offmask);
    k_deform<<<NPIX / PPB, dim3(256), 0, stream>>>(xt, offmask, wt, out);
}

// Round 2
// 716.107 us; speedup vs baseline: 2.0202x; 2.0202x over previous
//
#include <hip/hip_runtime.h>
#include <math.h>

// Problem constants
constexpr int B    = 2;
constexpr int C    = 64;    // input channels
constexpr int H    = 224;
constexpr int W    = 224;
constexpr int Hp   = 226;   // padded
constexpr int Wp   = 226;
constexpr int K2   = 9;     // 3x3
constexpr int OCO  = 18;    // offset channels (2*K2)
constexpr int OM   = 27;    // offset + mask channels
constexpr int COUT = 64;
constexpr int HW   = H * W;         // 50176
constexpr int NPIX = B * HW;        // 100352
constexpr int CK   = C * K2;        // 576

// ---------------------------------------------------------------------------
// Kernel P: x NCHW -> padded NHWC  xpadT[b][y+1][x+1][c]  (border pre-zeroed
// by hipMemsetAsync). LDS 32x32 tile transpose, coalesced both sides.
// ---------------------------------------------------------------------------
__global__ __launch_bounds__(256) void k_padT(const float* __restrict__ x,
                                              float* __restrict__ xp) {
    __shared__ float tile[32][33];
    const int b   = blockIdx.z;
    const int hw0 = blockIdx.x * 32;
    const int c0  = blockIdx.y * 32;
    const int tx  = threadIdx.x;   // 0..31
    const int ty  = threadIdx.y;   // 0..7
    const float* xb  = x  + (size_t)b * C * HW;
    float*       xpb = xp + (size_t)b * Hp * Wp * C;
#pragma unroll
    for (int j = 0; j < 4; ++j) {
        int c = c0 + ty + j * 8;
        tile[ty + j * 8][tx] = xb[(size_t)c * HW + hw0 + tx];
    }
    __syncthreads();
#pragma unroll
    for (int j = 0; j < 4; ++j) {
        int hw = hw0 + ty + j * 8;      // 32 | W so tile stays in one row
        int y  = hw / W;
        int xx = hw % W;
        xpb[((size_t)(y + 1) * Wp + (xx + 1)) * C + c0 + tx] = tile[tx][ty + j * 8];
    }
}

// ---------------------------------------------------------------------------
// Kernel T2: wt[(c*9+k)*64 + o] = w_deform[o][c][k]   (for k_deform phase 2)
// ---------------------------------------------------------------------------
__global__ void k_wt(const float* __restrict__ wd, float* __restrict__ wt) {
    int i = blockIdx.x * 256 + threadIdx.x;
    if (i >= CK * COUT) return;
    int o  = i & 63;
    int ck = i >> 6;          // c*9 + k
    int c  = ck / 9;
    int k  = ck % 9;
    wt[i] = wd[((size_t)o * C + c) * 9 + k];
}

// ---------------------------------------------------------------------------
// Kernel T3: wom2[(k*64+c)*27 + oc] = conv weights reordered so that for a
// fixed k the (c,oc) block is contiguous -> wave-uniform scalar loads.
// oc 0..17 = offset, 18..26 = mask.
// ---------------------------------------------------------------------------
__global__ void k_wom(const float* __restrict__ w_off,
                      const float* __restrict__ w_msk,
                      float* __restrict__ wom2) {
    int i = blockIdx.x * 256 + threadIdx.x;
    if (i >= 9 * C * OM) return;
    int oc = i % OM;
    int kc = i / OM;
    int c  = kc % C;
    int k  = kc / C;
    float v = (oc < OCO) ? w_off[((size_t)oc * C + c) * 9 + k]
                         : w_msk[((size_t)(oc - OCO) * C + c) * 9 + k];
    wom2[i] = v;
}

// ---------------------------------------------------------------------------
// Kernel C: offset+mask 3x3 conv. One thread = one pixel, ALL 27 output
// channels. x from padded NHWC (float4 channel loads), weights via uniform
// scalar loads. 15552 FMA / 144 float4-loads per thread -> VALU-bound.
// ---------------------------------------------------------------------------
__global__ __launch_bounds__(256) void k_convom(const float* __restrict__ xp,
                                                const float* __restrict__ wom2,
                                                const float* __restrict__ b_off,
                                                const float* __restrict__ b_msk,
                                                float* __restrict__ offmask) {
    const int pix = blockIdx.x * 256 + threadIdx.x;
    const int b   = pix / HW;
    const int hw  = pix % HW;
    const int y   = hw / W;
    const int xx  = hw % W;

    float acc[OM];
#pragma unroll
    for (int oc = 0; oc < OCO; ++oc) acc[oc] = b_off[oc];
#pragma unroll
    for (int oc = 0; oc < 9; ++oc) acc[OCO + oc] = b_msk[oc];

    const float* xb = xp + (size_t)b * Hp * Wp * C;
#pragma unroll
    for (int k = 0; k < 9; ++k) {
        const int ky = k / 3, kx = k % 3;
        // padded coords: (y+ky, xx+kx) in the Hp x Wp frame
        const float* xrow = xb + ((size_t)(y + ky) * Wp + (xx + kx)) * C;
        const float* wk   = wom2 + (size_t)k * C * OM;
        for (int c4 = 0; c4 < C / 4; ++c4) {
            const float4 xv = *reinterpret_cast<const float4*>(xrow + c4 * 4);
            const float* wc = wk + (size_t)c4 * 4 * OM;
#pragma unroll
            for (int j = 0; j < 4; ++j) {
                const float xs = j == 0 ? xv.x : j == 1 ? xv.y : j == 2 ? xv.z : xv.w;
#pragma unroll
                for (int oc = 0; oc < OM; ++oc)
                    acc[oc] = fmaf(xs, wc[j * OM + oc], acc[oc]);
            }
        }
    }

    float* om = offmask + (size_t)pix * OM;
#pragma unroll
    for (int oc = 0; oc < OCO; ++oc) om[oc] = acc[oc];
#pragma unroll
    for (int oc = 0; oc < 9; ++oc)
        om[OCO + oc] = 1.0f / (1.0f + __expf(-acc[OCO + oc]));
}

// ---------------------------------------------------------------------------
// Kernel D: deformable gather + per-pixel [64 x 576] contraction.
// 16 pixels per block, 256 threads.
//  Phase 1: lanes = channels; bilinear gather from padded NHWC -> LDS val.
//  Phase 2: lanes = out channels; 4 pixels per thread, float4 LDS broadcast.
// ---------------------------------------------------------------------------
constexpr int PPB  = 16;
constexpr int VSTR = 20;

__global__ __launch_bounds__(256) void k_deform(const float* __restrict__ xp,
                                                const float* __restrict__ offmask,
                                                const float* __restrict__ wt,
                                                float* __restrict__ out) {
    __shared__ __align__(16) float val[CK * VSTR];   // 576*20*4 = 46080 B
    const int tid  = threadIdx.x;
    const int pix0 = blockIdx.x * PPB;

    // ---- Phase 1: gather ----
    {
        const int c  = tid & 63;
        const int pl = tid >> 6;          // 0..3
        for (int po = 0; po < 4; ++po) {
            const int p   = po * 4 + pl;
            const int pix = pix0 + p;
            const int b   = pix / HW;
            const int hw  = pix % HW;
            const int ho  = hw / W;
            const int wo  = hw % W;
            const float* om = offmask + (size_t)pix * OM;
            const float* xb = xp + (size_t)b * Hp * Wp * C;
#pragma unroll
            for (int k = 0; k < K2; ++k) {
                const float dy = om[2 * k];
                const float dx = om[2 * k + 1];
                const float m  = om[OCO + k];
                const float py = dy + (float)(ho - 1 + k / 3);
                const float px = dx + (float)(wo - 1 + k % 3);
                const float fy = floorf(py);
                const float fx = floorf(px);
                const int   y0 = (int)fy;
                const int   x0 = (int)fx;
                const float wy1 = py - fy, wx1 = px - fx;
                const float wy0 = 1.0f - wy1, wx0 = 1.0f - wx1;
                float s = 0.0f;
                if (y0 >= 0 && y0 < H) {
                    const float* r0 = xb + ((size_t)(y0 + 1) * Wp) * C;
                    if (x0 >= 0 && x0 < W)
                        s += (wy0 * wx0) * r0[(size_t)(x0 + 1) * C + c];
                    if (x0 + 1 >= 0 && x0 + 1 < W)
                        s += (wy0 * wx1) * r0[(size_t)(x0 + 2) * C + c];
                }
                if (y0 + 1 >= 0 && y0 + 1 < H) {
                    const float* r1 = xb + ((size_t)(y0 + 2) * Wp) * C;
                    if (x0 >= 0 && x0 < W)
                        s += (wy1 * wx0) * r1[(size_t)(x0 + 1) * C + c];
                    if (x0 + 1 >= 0 && x0 + 1 < W)
                        s += (wy1 * wx1) * r1[(size_t)(x0 + 2) * C + c];
                }
                val[(c * 9 + k) * VSTR + p] = m * s;
            }
        }
    }
    __syncthreads();

    // ---- Phase 2: out[o][p] = sum_ck wt[ck][o] * val[ck][p] ----
    {
        const int o  = tid & 63;
        const int pg = tid >> 6;          // 0..3 -> pixels pg*4..pg*4+3
        float acc0 = 0.f, acc1 = 0.f, acc2 = 0.f, acc3 = 0.f;
        const float* wpo = wt + o;
#pragma unroll 4
        for (int ck = 0; ck < CK; ++ck) {
            const float  w = wpo[(size_t)ck * 64];
            const float4 v = *reinterpret_cast<const float4*>(&val[ck * VSTR + pg * 4]);
            acc0 = fmaf(w, v.x, acc0);
            acc1 = fmaf(w, v.y, acc1);
            acc2 = fmaf(w, v.z, acc2);
            acc3 = fmaf(w, v.w, acc3);
        }
        const int pix = pix0 + pg * 4;
        const int b   = pix / HW;
        const int hw  = pix % HW;         // pix..pix+3 stay in one row (16|HW)
        float4 r = make_float4(acc0, acc1, acc2, acc3);
        *reinterpret_cast<float4*>(&out[((size_t)b * COUT + o) * HW + hw]) = r;
    }
}

// ---------------------------------------------------------------------------
extern "C" void kernel_launch(void* const* d_in, const int* in_sizes, int n_in,
                              void* d_out, int out_size, void* d_ws, size_t ws_size,
                              hipStream_t stream) {
    const float* x     = (const float*)d_in[0];
    const float* w_off = (const float*)d_in[1];
    const float* b_off = (const float*)d_in[2];
    const float* w_msk = (const float*)d_in[3];
    const float* b_msk = (const float*)d_in[4];
    const float* w_def = (const float*)d_in[5];
    float* out = (float*)d_out;

    float* ws      = (float*)d_ws;
    float* xpadT   = ws;                                   // B*Hp*Wp*C
    float* offmask = xpadT + (size_t)B * Hp * Wp * C;      // NPIX*27
    float* wt      = offmask + (size_t)NPIX * OM;          // 576*64
    float* wom2    = wt + (size_t)CK * COUT;               // 9*64*27

    // zero the pad border (full clear is cheap: 26 MB)
    hipMemsetAsync(xpadT, 0, (size_t)B * Hp * Wp * C * sizeof(float), stream);

    k_padT<<<dim3(HW / 32, C / 32, B), dim3(32, 8), 0, stream>>>(x, xpadT);
    k_wt<<<(CK * COUT + 255) / 256, 256, 0, stream>>>(w_def, wt);
    k_wom<<<(9 * C * OM + 255) / 256, 256, 0, stream>>>(w_off, w_msk, wom2);
    k_convom<<<NPIX / 256, 256, 0, stream>>>(xpadT, wom2, b_off, b_msk, offmask);
    k_deform<<<NPIX / PPB, 256, 0, stream>>>(xpadT, offmask, wt, out);
}

// Round 3
// 280.804 us; speedup vs baseline: 5.1518x; 2.5502x over previous
//
#include <hip/hip_runtime.h>
#include <math.h>

// Problem constants
constexpr int B    = 2;
constexpr int C    = 64;
constexpr int H    = 224;
constexpr int W    = 224;
constexpr int Hp   = 226;   // padded
constexpr int Wp   = 226;
constexpr int K2   = 9;
constexpr int OCO  = 18;
constexpr int OM   = 27;
constexpr int COUT = 64;
constexpr int HW   = H * W;         // 50176
constexpr int NPIX = B * HW;        // 100352
constexpr int CK   = C * K2;        // 576

typedef short  bf16x8 __attribute__((ext_vector_type(8)));
typedef float  f32x4  __attribute__((ext_vector_type(4)));

__device__ inline unsigned short f2bf(float f) {
    union { float f; unsigned u; } v; v.f = f;
    unsigned r = v.u + 0x7FFF + ((v.u >> 16) & 1);   // RNE
    return (unsigned short)(r >> 16);
}
__device__ inline unsigned pack2(float a, float b) {
    return (unsigned)f2bf(a) | ((unsigned)f2bf(b) << 16);
}

// ---------------------------------------------------------------------------
// Kernel P: x NCHW -> padded NHWC  xpadT[b][y+1][x+1][c]
// ---------------------------------------------------------------------------
__global__ __launch_bounds__(256) void k_padT(const float* __restrict__ x,
                                              float* __restrict__ xp) {
    __shared__ float tile[32][33];
    const int b   = blockIdx.z;
    const int hw0 = blockIdx.x * 32;
    const int c0  = blockIdx.y * 32;
    const int tx  = threadIdx.x;
    const int ty  = threadIdx.y;
    const float* xb  = x  + (size_t)b * C * HW;
    float*       xpb = xp + (size_t)b * Hp * Wp * C;
#pragma unroll
    for (int j = 0; j < 4; ++j) {
        int c = c0 + ty + j * 8;
        tile[ty + j * 8][tx] = xb[(size_t)c * HW + hw0 + tx];
    }
    __syncthreads();
#pragma unroll
    for (int j = 0; j < 4; ++j) {
        int hw = hw0 + ty + j * 8;
        int y  = hw / W;
        int xx = hw % W;
        xpb[((size_t)(y + 1) * Wp + (xx + 1)) * C + c0 + tx] = tile[tx][ty + j * 8];
    }
}

// ---------------------------------------------------------------------------
// Kernel T2: wA[o][k*64+c] = bf16(w_deform[o][c][k])   (A operand of GEMM)
// ---------------------------------------------------------------------------
__global__ void k_wA(const float* __restrict__ wd, unsigned short* __restrict__ wA) {
    int i = blockIdx.x * 256 + threadIdx.x;
    if (i >= COUT * CK) return;
    int o  = i / CK;
    int kc = i % CK;
    int k  = kc >> 6;
    int c  = kc & 63;
    wA[i] = f2bf(wd[((size_t)o * C + c) * 9 + k]);
}

// ---------------------------------------------------------------------------
// Kernel T3: wom2[(k*64+c)*27 + oc]  (conv weights, wave-uniform scalar loads)
// ---------------------------------------------------------------------------
__global__ void k_wom(const float* __restrict__ w_off,
                      const float* __restrict__ w_msk,
                      float* __restrict__ wom2) {
    int i = blockIdx.x * 256 + threadIdx.x;
    if (i >= 9 * C * OM) return;
    int oc = i % OM;
    int kc = i / OM;
    int c  = kc % C;
    int k  = kc / C;
    float v = (oc < OCO) ? w_off[((size_t)oc * C + c) * 9 + k]
                         : w_msk[((size_t)(oc - OCO) * C + c) * 9 + k];
    wom2[i] = v;
}

// ---------------------------------------------------------------------------
// Kernel C: offset+mask 3x3 conv. One thread = one pixel, all 27 channels.
// ---------------------------------------------------------------------------
__global__ __launch_bounds__(256) void k_convom(const float* __restrict__ xp,
                                                const float* __restrict__ wom2,
                                                const float* __restrict__ b_off,
                                                const float* __restrict__ b_msk,
                                                float* __restrict__ offmask) {
    const int pix = blockIdx.x * 256 + threadIdx.x;
    const int b   = pix / HW;
    const int hw  = pix % HW;
    const int y   = hw / W;
    const int xx  = hw % W;

    float acc[OM];
#pragma unroll
    for (int oc = 0; oc < OCO; ++oc) acc[oc] = b_off[oc];
#pragma unroll
    for (int oc = 0; oc < 9; ++oc) acc[OCO + oc] = b_msk[oc];

    const float* xb = xp + (size_t)b * Hp * Wp * C;
#pragma unroll
    for (int k = 0; k < 9; ++k) {
        const int ky = k / 3, kx = k % 3;
        const float* xrow = xb + ((size_t)(y + ky) * Wp + (xx + kx)) * C;
        const float* wk   = wom2 + (size_t)k * C * OM;
        for (int c4 = 0; c4 < C / 4; ++c4) {
            const float4 xv = *reinterpret_cast<const float4*>(xrow + c4 * 4);
            const float* wc = wk + (size_t)c4 * 4 * OM;
#pragma unroll
            for (int j = 0; j < 4; ++j) {
                const float xs = j == 0 ? xv.x : j == 1 ? xv.y : j == 2 ? xv.z : xv.w;
#pragma unroll
                for (int oc = 0; oc < OM; ++oc)
                    acc[oc] = fmaf(xs, wc[j * OM + oc], acc[oc]);
            }
        }
    }

    float* om = offmask + (size_t)pix * OM;
#pragma unroll
    for (int oc = 0; oc < OCO; ++oc) om[oc] = acc[oc];
#pragma unroll
    for (int oc = 0; oc < 9; ++oc)
        om[OCO + oc] = 1.0f / (1.0f + __expf(-acc[OCO + oc]));
}

// ---------------------------------------------------------------------------
// Kernel D: deformable gather (fp32 -> bf16 LDS) + MFMA contraction.
// Block = 64 pixels, 256 threads, LDS valT[64 pix][576 kc] bf16 (72 KB),
// XOR-swizzled (byte ^= (row&7)<<4) for conflict-free b128 access.
// GEMM: out[64 o][64 pix] = wA[64 o][576] x valT[576][64 pix], K-order k*64+c.
// Each wave: m-tile = 16 o-rows, full 64 pix (4 n-tiles), 18 K-steps.
// ---------------------------------------------------------------------------
constexpr int PPB = 64;

__global__ __launch_bounds__(256) void k_deform(const float* __restrict__ xp,
                                                const float* __restrict__ offmask,
                                                const unsigned short* __restrict__ wA,
                                                float* __restrict__ out) {
    __shared__ __align__(16) unsigned short valT[64 * CK];   // 72 KB
    const int tid  = threadIdx.x;
    const int lane = tid & 63;
    const int wv   = tid >> 6;          // wave 0..3
    const int q    = lane >> 4;         // quarter 0..3
    const int l15  = lane & 15;
    const int pix0 = blockIdx.x * PPB;
    const int bb   = pix0 / HW;         // batch (uniform per block)
    const float* xb = xp + (size_t)bb * Hp * Wp * C;

    // ---- Phase 1: bilinear gather, 4 channels/thread, bf16 -> LDS ----
    const int c0 = l15 * 4;
    for (int pi = 0; pi < 4; ++pi) {
        const int p_local = wv * 16 + pi * 4 + q;
        const int pix = pix0 + p_local;
        const int hw  = pix - bb * HW;
        const int ho  = hw / W;
        const int wo  = hw % W;
        const float* om = offmask + (size_t)pix * OM;
#pragma unroll 3
        for (int k = 0; k < 9; ++k) {
            const float dy = om[2 * k];
            const float dx = om[2 * k + 1];
            const float m  = om[OCO + k];
            const float py = dy + (float)(ho - 1 + k / 3);
            const float px = dx + (float)(wo - 1 + k % 3);
            const float fy = floorf(py), fx = floorf(px);
            const int   y0 = (int)fy,   x0 = (int)fx;
            const float wy1 = py - fy,  wx1 = px - fx;
            const float wy0 = 1.f - wy1, wx0 = 1.f - wx1;
            // validity per corner (reference semantics)
            const bool iy0 = (y0 >= 0) & (y0 < H);
            const bool iy1 = (y0 + 1 >= 0) & (y0 + 1 < H);
            const bool ix0 = (x0 >= 0) & (x0 < W);
            const bool ix1 = (x0 + 1 >= 0) & (x0 + 1 < W);
            const float w00 = wy0 * wx0 * ((iy0 & ix0) ? 1.f : 0.f);
            const float w01 = wy0 * wx1 * ((iy0 & ix1) ? 1.f : 0.f);
            const float w10 = wy1 * wx0 * ((iy1 & ix0) ? 1.f : 0.f);
            const float w11 = wy1 * wx1 * ((iy1 & ix1) ? 1.f : 0.f);
            // clamped padded coords -> unconditional coalesced float4 loads
            const int ya = min(max(y0 + 1, 0), Hp - 1);
            const int yb = min(max(y0 + 2, 0), Hp - 1);
            const int xa = min(max(x0 + 1, 0), Wp - 1);
            const int xc = min(max(x0 + 2, 0), Wp - 1);
            const float4 v00 = *reinterpret_cast<const float4*>(xb + ((size_t)ya * Wp + xa) * C + c0);
            const float4 v01 = *reinterpret_cast<const float4*>(xb + ((size_t)ya * Wp + xc) * C + c0);
            const float4 v10 = *reinterpret_cast<const float4*>(xb + ((size_t)yb * Wp + xa) * C + c0);
            const float4 v11 = *reinterpret_cast<const float4*>(xb + ((size_t)yb * Wp + xc) * C + c0);
            const float s0 = m * (w00 * v00.x + w01 * v01.x + w10 * v10.x + w11 * v11.x);
            const float s1 = m * (w00 * v00.y + w01 * v01.y + w10 * v10.y + w11 * v11.y);
            const float s2 = m * (w00 * v00.z + w01 * v01.z + w10 * v10.z + w11 * v11.z);
            const float s3 = m * (w00 * v00.w + w01 * v01.w + w10 * v10.w + w11 * v11.w);
            // valT[p_local][k*64 + c0..c0+3], swizzled
            int byte = p_local * (CK * 2) + k * 128 + l15 * 8;
            byte ^= (p_local & 7) << 4;
            *reinterpret_cast<uint2*>(reinterpret_cast<char*>(valT) + byte) =
                make_uint2(pack2(s0, s1), pack2(s2, s3));
        }
    }
    __syncthreads();

    // ---- Phase 2: MFMA GEMM ----
    f32x4 acc[4] = {{0.f,0.f,0.f,0.f},{0.f,0.f,0.f,0.f},{0.f,0.f,0.f,0.f},{0.f,0.f,0.f,0.f}};
    const unsigned short* wrow = wA + (size_t)(wv * 16 + l15) * CK;
#pragma unroll 3
    for (int ks = 0; ks < 18; ++ks) {
        const bf16x8 af = *reinterpret_cast<const bf16x8*>(wrow + ks * 32 + q * 8);
#pragma unroll
        for (int nt = 0; nt < 4; ++nt) {
            const int row = nt * 16 + l15;
            int byte = row * (CK * 2) + ks * 64 + q * 16;
            byte ^= (row & 7) << 4;
            const bf16x8 bfv = *reinterpret_cast<const bf16x8*>(
                reinterpret_cast<const char*>(valT) + byte);
            acc[nt] = __builtin_amdgcn_mfma_f32_16x16x32_bf16(af, bfv, acc[nt], 0, 0, 0);
        }
    }

    // ---- Store: D[o = wv*16 + q*4 + r][pix = pix0 + nt*16 + l15] ----
    const int o0 = wv * 16 + q * 4;
#pragma unroll
    for (int nt = 0; nt < 4; ++nt) {
        const int pixn = pix0 + nt * 16 + l15;
        const int hw   = pixn - bb * HW;
#pragma unroll
        for (int r = 0; r < 4; ++r)
            out[((size_t)bb * COUT + o0 + r) * HW + hw] = acc[nt][r];
    }
}

// ---------------------------------------------------------------------------
extern "C" void kernel_launch(void* const* d_in, const int* in_sizes, int n_in,
                              void* d_out, int out_size, void* d_ws, size_t ws_size,
                              hipStream_t stream) {
    const float* x     = (const float*)d_in[0];
    const float* w_off = (const float*)d_in[1];
    const float* b_off = (const float*)d_in[2];
    const float* w_msk = (const float*)d_in[3];
    const float* b_msk = (const float*)d_in[4];
    const float* w_def = (const float*)d_in[5];
    float* out = (float*)d_out;

    float* ws      = (float*)d_ws;
    float* xpadT   = ws;                                   // B*Hp*Wp*C floats
    float* offmask = xpadT + (size_t)B * Hp * Wp * C;      // NPIX*27
    float* wom2    = offmask + (size_t)NPIX * OM;          // 9*64*27
    unsigned short* wA = (unsigned short*)(wom2 + (size_t)9 * C * OM); // 64*576 bf16

    hipMemsetAsync(xpadT, 0, (size_t)B * Hp * Wp * C * sizeof(float), stream);

    k_padT<<<dim3(HW / 32, C / 32, B), dim3(32, 8), 0, stream>>>(x, xpadT);
    k_wA<<<(COUT * CK + 255) / 256, 256, 0, stream>>>(w_def, wA);
    k_wom<<<(9 * C * OM + 255) / 256, 256, 0, stream>>>(w_off, w_msk, wom2);
    k_convom<<<NPIX / 256, 256, 0, stream>>>(xpadT, wom2, b_off, b_msk, offmask);
    k_deform<<<NPIX / PPB, 256, 0, stream>>>(xpadT, offmask, wA, out);
}

// Round 5
// 218.961 us; speedup vs baseline: 6.6069x; 1.2824x over previous
//
#include <hip/hip_runtime.h>
#include <math.h>

// Problem constants
constexpr int B    = 2;
constexpr int C    = 64;
constexpr int H    = 224;
constexpr int W    = 224;
constexpr int Hp   = 226;   // padded
constexpr int Wp   = 226;
constexpr int K2   = 9;
constexpr int OCO  = 18;
constexpr int OM   = 27;
constexpr int COUT = 64;
constexpr int HW   = H * W;         // 50176
constexpr int NPIX = B * HW;        // 100352
constexpr int CK   = C * K2;        // 576

typedef short  bf16x8 __attribute__((ext_vector_type(8)));
typedef float  f32x4  __attribute__((ext_vector_type(4)));

__device__ inline unsigned short f2bf(float f) {
    union { float f; unsigned u; } v; v.f = f;
    unsigned r = v.u + 0x7FFF + ((v.u >> 16) & 1);   // RNE
    return (unsigned short)(r >> 16);
}
__device__ inline unsigned pack2(float a, float b) {
    return (unsigned)f2bf(a) | ((unsigned)f2bf(b) << 16);
}

// ---------------------------------------------------------------------------
// Kernel P: x NCHW -> padded NHWC  xpadT[b][y+1][x+1][c]
// ---------------------------------------------------------------------------
__global__ __launch_bounds__(256) void k_padT(const float* __restrict__ x,
                                              float* __restrict__ xp) {
    __shared__ float tile[32][33];
    const int b   = blockIdx.z;
    const int hw0 = blockIdx.x * 32;
    const int c0  = blockIdx.y * 32;
    const int tx  = threadIdx.x;
    const int ty  = threadIdx.y;
    const float* xb  = x  + (size_t)b * C * HW;
    float*       xpb = xp + (size_t)b * Hp * Wp * C;
#pragma unroll
    for (int j = 0; j < 4; ++j) {
        int c = c0 + ty + j * 8;
        tile[ty + j * 8][tx] = xb[(size_t)c * HW + hw0 + tx];
    }
    __syncthreads();
#pragma unroll
    for (int j = 0; j < 4; ++j) {
        int hw = hw0 + ty + j * 8;
        int y  = hw / W;
        int xx = hw % W;
        xpb[((size_t)(y + 1) * Wp + (xx + 1)) * C + c0 + tx] = tile[tx][ty + j * 8];
    }
}

// ---------------------------------------------------------------------------
// Kernel T2: wA[o][k*64+c] = bf16(w_deform[o][c][k])   (A operand, deform GEMM)
// ---------------------------------------------------------------------------
__global__ void k_wA(const float* __restrict__ wd, unsigned short* __restrict__ wA) {
    int i = blockIdx.x * 256 + threadIdx.x;
    if (i >= COUT * CK) return;
    int o  = i / CK;
    int kc = i % CK;
    int k  = kc >> 6;
    int c  = kc & 63;
    wA[i] = f2bf(wd[((size_t)o * C + c) * 9 + k]);
}

// ---------------------------------------------------------------------------
// Kernel T3: womA[oc][k*64+c] bf16, oc 0..17 offset / 18..26 mask / 27..31 zero
//            biasv[32]: matching biases.
// ---------------------------------------------------------------------------
__global__ void k_womA(const float* __restrict__ w_off,
                       const float* __restrict__ w_msk,
                       const float* __restrict__ b_off,
                       const float* __restrict__ b_msk,
                       unsigned short* __restrict__ womA,
                       float* __restrict__ biasv) {
    int i = blockIdx.x * 256 + threadIdx.x;
    if (i < 32) biasv[i] = (i < OCO) ? b_off[i] : (i < OM) ? b_msk[i - OCO] : 0.f;
    if (i >= 32 * CK) return;
    int oc = i / CK;
    int kc = i % CK;
    int k  = kc >> 6;
    int c  = kc & 63;
    float v = (oc < OCO) ? w_off[((size_t)oc * C + c) * 9 + k]
            : (oc < OM)  ? w_msk[((size_t)(oc - OCO) * C + c) * 9 + k]
                         : 0.f;
    womA[i] = f2bf(v);
}

// ---------------------------------------------------------------------------
// Kernel C: offset+mask conv as MFMA GEMM.
// out[27][64pix] = womA[32][576] x im2col[576][64pix] per 64-pixel block.
// LDS imcol[64 pix][576], bf16, XOR-swizzled (byte ^= (row&7)<<4).
// Wave w: n-tile = w (16 pixels), m-tiles 0 and 1.
// ---------------------------------------------------------------------------
__global__ __launch_bounds__(256) void k_convom(const float* __restrict__ xp,
                                                const unsigned short* __restrict__ womA,
                                                const float* __restrict__ biasv,
                                                float* __restrict__ offmask) {
    __shared__ __align__(16) unsigned short imcol[64 * CK];   // 72 KB
    const int tid  = threadIdx.x;
    const int lane = tid & 63;
    const int wv   = tid >> 6;
    const int q    = lane >> 4;
    const int l15  = lane & 15;
    const int pix0 = blockIdx.x * 64;
    const int bb   = pix0 / HW;          // block never spans batches (64|HW)
    const float* xb = xp + (size_t)bb * Hp * Wp * C;

    // ---- Phase 1: im2col -> bf16 LDS ----
    const int c0 = l15 * 4;
    for (int pi = 0; pi < 4; ++pi) {
        const int p_local = wv * 16 + pi * 4 + q;
        const int pix = pix0 + p_local;
        const int hw  = pix - bb * HW;
        const int y   = hw / W;
        const int xx  = hw % W;
#pragma unroll
        for (int k = 0; k < 9; ++k) {
            const int ky = k / 3, kx = k % 3;
            const float4 v = *reinterpret_cast<const float4*>(
                xb + ((size_t)(y + ky) * Wp + (xx + kx)) * C + c0);
            int byte = p_local * (CK * 2) + k * 128 + l15 * 8;
            byte ^= (p_local & 7) << 4;
            *reinterpret_cast<uint2*>(reinterpret_cast<char*>(imcol) + byte) =
                make_uint2(pack2(v.x, v.y), pack2(v.z, v.w));
        }
    }
    __syncthreads();

    // ---- Phase 2: MFMA ----
    f32x4 acc0 = {0.f, 0.f, 0.f, 0.f}, acc1 = {0.f, 0.f, 0.f, 0.f};
    const unsigned short* a0 = womA + (size_t)l15 * CK;
    const unsigned short* a1 = womA + (size_t)(16 + l15) * CK;
    const int row = wv * 16 + l15;
#pragma unroll 3
    for (int ks = 0; ks < 18; ++ks) {
        int byte = row * (CK * 2) + ks * 64 + q * 16;
        byte ^= (row & 7) << 4;
        const bf16x8 bfv = *reinterpret_cast<const bf16x8*>(
            reinterpret_cast<const char*>(imcol) + byte);
        const bf16x8 af0 = *reinterpret_cast<const bf16x8*>(a0 + ks * 32 + q * 8);
        const bf16x8 af1 = *reinterpret_cast<const bf16x8*>(a1 + ks * 32 + q * 8);
        acc0 = __builtin_amdgcn_mfma_f32_16x16x32_bf16(af0, bfv, acc0, 0, 0, 0);
        acc1 = __builtin_amdgcn_mfma_f32_16x16x32_bf16(af1, bfv, acc1, 0, 0, 0);
    }

    // ---- Epilogue: bias (+sigmoid for mask rows), store offmask[pix][27] ----
    const int  pixn = pix0 + wv * 16 + l15;
    float* om = offmask + (size_t)pixn * OM;
#pragma unroll
    for (int r = 0; r < 4; ++r) {
        const int oc = q * 4 + r;                 // 0..15: raw offsets
        om[oc] = acc0[r] + biasv[oc];
    }
#pragma unroll
    for (int r = 0; r < 4; ++r) {
        const int oc = 16 + q * 4 + r;            // 16..31
        if (oc < OM) {
            float v = acc1[r] + biasv[oc];
            om[oc] = (oc < OCO) ? v : 1.0f / (1.0f + __expf(-v));
        }
    }
}

// ---------------------------------------------------------------------------
// Kernel D: deformable gather (fp32 -> bf16 LDS) + MFMA contraction.
// ---------------------------------------------------------------------------
constexpr int PPB = 64;

__global__ __launch_bounds__(256) void k_deform(const float* __restrict__ xp,
                                                const float* __restrict__ offmask,
                                                const unsigned short* __restrict__ wA,
                                                float* __restrict__ out) {
    __shared__ __align__(16) unsigned short valT[64 * CK];   // 72 KB
    const int tid  = threadIdx.x;
    const int lane = tid & 63;
    const int wv   = tid >> 6;
    const int q    = lane >> 4;
    const int l15  = lane & 15;
    const int pix0 = blockIdx.x * PPB;
    const int bb   = pix0 / HW;
    const float* xb = xp + (size_t)bb * Hp * Wp * C;

    // ---- Phase 1: bilinear gather, 4 channels/thread, bf16 -> LDS ----
    const int c0 = l15 * 4;
    for (int pi = 0; pi < 4; ++pi) {
        const int p_local = wv * 16 + pi * 4 + q;
        const int pix = pix0 + p_local;
        const int hw  = pix - bb * HW;
        const int ho  = hw / W;
        const int wo  = hw % W;
        const float* om = offmask + (size_t)pix * OM;
#pragma unroll 3
        for (int k = 0; k < 9; ++k) {
            const float dy = om[2 * k];
            const float dx = om[2 * k + 1];
            const float m  = om[OCO + k];
            const float py = dy + (float)(ho - 1 + k / 3);
            const float px = dx + (float)(wo - 1 + k % 3);
            const float fy = floorf(py), fx = floorf(px);
            const int   y0 = (int)fy,   x0 = (int)fx;
            const float wy1 = py - fy,  wx1 = px - fx;
            const float wy0 = 1.f - wy1, wx0 = 1.f - wx1;
            const bool iy0 = (y0 >= 0) & (y0 < H);
            const bool iy1 = (y0 + 1 >= 0) & (y0 + 1 < H);
            const bool ix0 = (x0 >= 0) & (x0 < W);
            const bool ix1 = (x0 + 1 >= 0) & (x0 + 1 < W);
            const float w00 = wy0 * wx0 * ((iy0 & ix0) ? 1.f : 0.f);
            const float w01 = wy0 * wx1 * ((iy0 & ix1) ? 1.f : 0.f);
            const float w10 = wy1 * wx0 * ((iy1 & ix0) ? 1.f : 0.f);
            const float w11 = wy1 * wx1 * ((iy1 & ix1) ? 1.f : 0.f);
            const int ya = min(max(y0 + 1, 0), Hp - 1);
            const int yb = min(max(y0 + 2, 0), Hp - 1);
            const int xa = min(max(x0 + 1, 0), Wp - 1);
            const int xc = min(max(x0 + 2, 0), Wp - 1);
            const float4 v00 = *reinterpret_cast<const float4*>(xb + ((size_t)ya * Wp + xa) * C + c0);
            const float4 v01 = *reinterpret_cast<const float4*>(xb + ((size_t)ya * Wp + xc) * C + c0);
            const float4 v10 = *reinterpret_cast<const float4*>(xb + ((size_t)yb * Wp + xa) * C + c0);
            const float4 v11 = *reinterpret_cast<const float4*>(xb + ((size_t)yb * Wp + xc) * C + c0);
            const float s0 = m * (w00 * v00.x + w01 * v01.x + w10 * v10.x + w11 * v11.x);
            const float s1 = m * (w00 * v00.y + w01 * v01.y + w10 * v10.y + w11 * v11.y);
            const float s2 = m * (w00 * v00.z + w01 * v01.z + w10 * v10.z + w11 * v11.z);
            const float s3 = m * (w00 * v00.w + w01 * v01.w + w10 * v10.w + w11 * v11.w);
            int byte = p_local * (CK * 2) + k * 128 + l15 * 8;
            byte ^= (p_local & 7) << 4;
            *reinterpret_cast<uint2*>(reinterpret_cast<char*>(valT) + byte) =
                make_uint2(pack2(s0, s1), pack2(s2, s3));
        }
    }
    __syncthreads();

    // ---- Phase 2: MFMA GEMM ----
    f32x4 acc[4] = {{0.f,0.f,0.f,0.f},{0.f,0.f,0.f,0.f},{0.f,0.f,0.f,0.f},{0.f,0.f,0.f,0.f}};
    const unsigned short* wrow = wA + (size_t)(wv * 16 + l15) * CK;
#pragma unroll 3
    for (int ks = 0; ks < 18; ++ks) {
        const bf16x8 af = *reinterpret_cast<const bf16x8*>(wrow + ks * 32 + q * 8);
#pragma unroll
        for (int nt = 0; nt < 4; ++nt) {
            const int row = nt * 16 + l15;
            int byte = row * (CK * 2) + ks * 64 + q * 16;
            byte ^= (row & 7) << 4;
            const bf16x8 bfv = *reinterpret_cast<const bf16x8*>(
                reinterpret_cast<const char*>(valT) + byte);
            acc[nt] = __builtin_amdgcn_mfma_f32_16x16x32_bf16(af, bfv, acc[nt], 0, 0, 0);
        }
    }

    // ---- Store ----
    const int o0 = wv * 16 + q * 4;
#pragma unroll
    for (int nt = 0; nt < 4; ++nt) {
        const int pixn = pix0 + nt * 16 + l15;
        const int hw   = pixn - bb * HW;
#pragma unroll
        for (int r = 0; r < 4; ++r)
            out[((size_t)bb * COUT + o0 + r) * HW + hw] = acc[nt][r];
    }
}

// ---------------------------------------------------------------------------
extern "C" void kernel_launch(void* const* d_in, const int* in_sizes, int n_in,
                              void* d_out, int out_size, void* d_ws, size_t ws_size,
                              hipStream_t stream) {
    const float* x     = (const float*)d_in[0];
    const float* w_off = (const float*)d_in[1];
    const float* b_off = (const float*)d_in[2];
    const float* w_msk = (const float*)d_in[3];
    const float* b_msk = (const float*)d_in[4];
    const float* w_def = (const float*)d_in[5];
    float* out = (float*)d_out;

    float* ws      = (float*)d_ws;
    float* xpadT   = ws;                                   // B*Hp*Wp*C floats
    float* offmask = xpadT + (size_t)B * Hp * Wp * C;      // NPIX*27 floats
    float* biasv   = offmask + (size_t)NPIX * OM;          // 32 floats
    unsigned short* wA   = (unsigned short*)(biasv + 32);  // 64*576 bf16
    unsigned short* womA = wA + (size_t)COUT * CK;         // 32*576 bf16

    hipMemsetAsync(xpadT, 0, (size_t)B * Hp * Wp * C * sizeof(float), stream);

    k_padT<<<dim3(HW / 32, C / 32, B), dim3(32, 8), 0, stream>>>(x, xpadT);
    k_wA<<<(COUT * CK + 255) / 256, 256, 0, stream>>>(w_def, wA);
    k_womA<<<(32 * CK + 255) / 256, 256, 0, stream>>>(w_off, w_msk, b_off, b_msk,
                                                      womA, biasv);
    k_convom<<<NPIX / 64, 256, 0, stream>>>(xpadT, womA, biasv, offmask);
    k_deform<<<NPIX / PPB, 256, 0, stream>>>(xpadT, offmask, wA, out);
}

// Round 6
// 204.391 us; speedup vs baseline: 7.0779x; 1.0713x over previous
//
#include <hip/hip_runtime.h>
#include <hip/hip_bf16.h>
#include <math.h>

// Problem constants
constexpr int B    = 2;
constexpr int C    = 64;
constexpr int H    = 224;
constexpr int W    = 224;
constexpr int Hp   = 226;   // padded
constexpr int Wp   = 226;
constexpr int K2   = 9;
constexpr int OCO  = 18;
constexpr int OM   = 27;
constexpr int COUT = 64;
constexpr int HW   = H * W;         // 50176
constexpr int NPIX = B * HW;        // 100352
constexpr int CK   = C * K2;        // 576

typedef short  bf16x8 __attribute__((ext_vector_type(8)));
typedef float  f32x4  __attribute__((ext_vector_type(4)));

__device__ inline unsigned short f2bf(float f) {
    union { float f; unsigned u; } v; v.f = f;
    unsigned r = v.u + 0x7FFF + ((v.u >> 16) & 1);   // RNE
    return (unsigned short)(r >> 16);
}
// packed f32x2 -> bf16x2 via compiler (emits v_cvt_pk_bf16_f32 on gfx950)
__device__ inline unsigned cvtpk(float a, float b) {
    __hip_bfloat162 h = __float22bfloat162_rn(make_float2(a, b));
    union { __hip_bfloat162 h; unsigned u; } cv; cv.h = h;
    return cv.u;
}

// ---------------------------------------------------------------------------
// Kernel P: x NCHW -> padded NHWC  xpadT[b][y+1][x+1][c]  (interior only)
// ---------------------------------------------------------------------------
__global__ __launch_bounds__(256) void k_padT(const float* __restrict__ x,
                                              float* __restrict__ xp) {
    __shared__ float tile[32][33];
    const int b   = blockIdx.z;
    const int hw0 = blockIdx.x * 32;
    const int c0  = blockIdx.y * 32;
    const int tx  = threadIdx.x;
    const int ty  = threadIdx.y;
    const float* xb  = x  + (size_t)b * C * HW;
    float*       xpb = xp + (size_t)b * Hp * Wp * C;
#pragma unroll
    for (int j = 0; j < 4; ++j) {
        int c = c0 + ty + j * 8;
        tile[ty + j * 8][tx] = xb[(size_t)c * HW + hw0 + tx];
    }
    __syncthreads();
#pragma unroll
    for (int j = 0; j < 4; ++j) {
        int hw = hw0 + ty + j * 8;
        int y  = hw / W;
        int xx = hw % W;
        xpb[((size_t)(y + 1) * Wp + (xx + 1)) * C + c0 + tx] = tile[tx][ty + j * 8];
    }
}

// ---------------------------------------------------------------------------
// Kernel B: zero the pad border (900 cells/batch x 64 ch) — replaces memset.
// ---------------------------------------------------------------------------
__global__ void k_border(float* __restrict__ xp) {
    int i = blockIdx.x * 256 + threadIdx.x;   // B*900*16 float4-chunks
    if (i >= B * 900 * 16) return;
    int chunk = i & 15;
    int cell  = (i >> 4) % 900;
    int b     = (i >> 4) / 900;
    int y, x;
    if      (cell < 226) { y = 0;              x = cell; }
    else if (cell < 452) { y = Hp - 1;         x = cell - 226; }
    else if (cell < 676) { y = cell - 452 + 1; x = 0; }
    else                 { y = cell - 676 + 1; x = Wp - 1; }
    float4 z = make_float4(0.f, 0.f, 0.f, 0.f);
    *reinterpret_cast<float4*>(xp + ((size_t)b * Hp * Wp + y * Wp + x) * C + chunk * 4) = z;
}

// ---------------------------------------------------------------------------
// Kernel T2: wA[o][k*64+c] = bf16(w_deform[o][c][k])   (A operand, deform GEMM)
// ---------------------------------------------------------------------------
__global__ void k_wA(const float* __restrict__ wd, unsigned short* __restrict__ wA) {
    int i = blockIdx.x * 256 + threadIdx.x;
    if (i >= COUT * CK) return;
    int o  = i / CK;
    int kc = i % CK;
    int k  = kc >> 6;
    int c  = kc & 63;
    wA[i] = f2bf(wd[((size_t)o * C + c) * 9 + k]);
}

// ---------------------------------------------------------------------------
// Kernel T3: womA[oc][k*64+c] bf16 (27..31 zero) + biasv[32]
// ---------------------------------------------------------------------------
__global__ void k_womA(const float* __restrict__ w_off,
                       const float* __restrict__ w_msk,
                       const float* __restrict__ b_off,
                       const float* __restrict__ b_msk,
                       unsigned short* __restrict__ womA,
                       float* __restrict__ biasv) {
    int i = blockIdx.x * 256 + threadIdx.x;
    if (i < 32) biasv[i] = (i < OCO) ? b_off[i] : (i < OM) ? b_msk[i - OCO] : 0.f;
    if (i >= 32 * CK) return;
    int oc = i / CK;
    int kc = i % CK;
    int k  = kc >> 6;
    int c  = kc & 63;
    float v = (oc < OCO) ? w_off[((size_t)oc * C + c) * 9 + k]
            : (oc < OM)  ? w_msk[((size_t)(oc - OCO) * C + c) * 9 + k]
                         : 0.f;
    womA[i] = f2bf(v);
}

// ---------------------------------------------------------------------------
// Kernel C: offset+mask conv as MFMA GEMM + bilinear-plan epilogue.
// GEMM: [32 oc][576] x im2col[576][64 pix].  Then per (pix,k) compute the
// gather plan: int4 clamped corner offsets + float4 validity*mask-folded
// bilinear weights -> gtabO/gtabW.  (offmask never hits global.)
// ---------------------------------------------------------------------------
__global__ __launch_bounds__(256) void k_convom(const float* __restrict__ xp,
                                                const unsigned short* __restrict__ womA,
                                                const float* __restrict__ biasv,
                                                int4* __restrict__ gtabO,
                                                float4* __restrict__ gtabW) {
    __shared__ __align__(16) unsigned short imcol[64 * CK];   // 72 KB
    const int tid  = threadIdx.x;
    const int lane = tid & 63;
    const int wv   = tid >> 6;
    const int q    = lane >> 4;
    const int l15  = lane & 15;
    const int pix0 = blockIdx.x * 64;
    const int bb   = pix0 / HW;          // block never spans batches (64|HW)
    const float* xb = xp + (size_t)bb * Hp * Wp * C;

    // ---- Phase 1: im2col -> bf16 LDS ----
    const int c0 = l15 * 4;
    for (int pi = 0; pi < 4; ++pi) {
        const int p_local = wv * 16 + pi * 4 + q;
        const int pix = pix0 + p_local;
        const int hw  = pix - bb * HW;
        const int y   = hw / W;
        const int xx  = hw % W;
        int wbase = p_local * (CK * 2) + l15 * 8;
        wbase ^= (p_local & 7) << 4;
#pragma unroll
        for (int k = 0; k < 9; ++k) {
            const int ky = k / 3, kx = k % 3;
            const float4 v = *reinterpret_cast<const float4*>(
                xb + ((size_t)(y + ky) * Wp + (xx + kx)) * C + c0);
            *reinterpret_cast<uint2*>(reinterpret_cast<char*>(imcol) + wbase + k * 128) =
                make_uint2(cvtpk(v.x, v.y), cvtpk(v.z, v.w));
        }
    }
    __syncthreads();

    // ---- Phase 2: MFMA ----
    f32x4 acc0 = {0.f, 0.f, 0.f, 0.f}, acc1 = {0.f, 0.f, 0.f, 0.f};
    const unsigned short* a0 = womA + (size_t)l15 * CK;
    const unsigned short* a1 = womA + (size_t)(16 + l15) * CK;
    const int row = wv * 16 + l15;
#pragma unroll 3
    for (int ks = 0; ks < 18; ++ks) {
        int byte = row * (CK * 2) + ks * 64 + q * 16;
        byte ^= (row & 7) << 4;
        const bf16x8 bfv = *reinterpret_cast<const bf16x8*>(
            reinterpret_cast<const char*>(imcol) + byte);
        const bf16x8 af0 = *reinterpret_cast<const bf16x8*>(a0 + ks * 32 + q * 8);
        const bf16x8 af1 = *reinterpret_cast<const bf16x8*>(a1 + ks * 32 + q * 8);
        acc0 = __builtin_amdgcn_mfma_f32_16x16x32_bf16(af0, bfv, acc0, 0, 0, 0);
        acc1 = __builtin_amdgcn_mfma_f32_16x16x32_bf16(af1, bfv, acc1, 0, 0, 0);
    }

    // ---- Epilogue A: stash raw offsets + sigmoid(mask) into LDS ----
    __syncthreads();                       // all imcol reads done; reuse LDS
    float* som = reinterpret_cast<float*>(imcol);   // [64][28] floats
    {
        const int p = wv * 16 + l15;
#pragma unroll
        for (int r = 0; r < 4; ++r) {
            const int oc = q * 4 + r;                     // 0..15
            som[p * 28 + oc] = acc0[r] + biasv[oc];
        }
#pragma unroll
        for (int r = 0; r < 4; ++r) {
            const int oc = 16 + q * 4 + r;                // 16..31
            if (oc < OM) {
                float v = acc1[r] + biasv[oc];
                som[p * 28 + oc] = (oc < OCO) ? v : 1.0f / (1.0f + __expf(-v));
            }
        }
    }
    __syncthreads();

    // ---- Epilogue B: bilinear plan per (pix,k) -> gtab ----
    for (int e = tid; e < 64 * 9; e += 256) {
        const int p  = e / 9;
        const int k  = e - p * 9;
        const int pix = pix0 + p;
        const int hw  = pix - bb * HW;
        const int ho  = hw / W;
        const int wo  = hw - ho * W;
        const int ky  = k / 3, kx = k - (k / 3) * 3;
        const float dy = som[p * 28 + 2 * k];
        const float dx = som[p * 28 + 2 * k + 1];
        const float m  = som[p * 28 + OCO + k];
        const float py = dy + (float)(ho + ky - 1);
        const float px = dx + (float)(wo + kx - 1);
        const float fy = floorf(py), fx = floorf(px);
        const int   y0 = (int)fy,   x0 = (int)fx;
        const float wy1 = py - fy,  wx1 = px - fx;
        const float wy0 = 1.f - wy1, wx0 = 1.f - wx1;
        const bool iy0 = (y0 >= 0) & (y0 < H);
        const bool iy1 = (y0 + 1 >= 0) & (y0 + 1 < H);
        const bool ix0 = (x0 >= 0) & (x0 < W);
        const bool ix1 = (x0 + 1 >= 0) & (x0 + 1 < W);
        const int ya = min(max(y0 + 1, 0), Hp - 1);
        const int yb = min(max(y0 + 2, 0), Hp - 1);
        const int xa = min(max(x0 + 1, 0), Wp - 1);
        const int xc = min(max(x0 + 2, 0), Wp - 1);
        const int rA = ya * Wp, rB = yb * Wp;
        gtabO[(size_t)pix * 9 + k] = make_int4((rA + xa) * C, (rA + xc) * C,
                                               (rB + xa) * C, (rB + xc) * C);
        gtabW[(size_t)pix * 9 + k] = make_float4(
            wy0 * wx0 * m * ((iy0 & ix0) ? 1.f : 0.f),
            wy0 * wx1 * m * ((iy0 & ix1) ? 1.f : 0.f),
            wy1 * wx0 * m * ((iy1 & ix0) ? 1.f : 0.f),
            wy1 * wx1 * m * ((iy1 & ix1) ? 1.f : 0.f));
    }
}

// ---------------------------------------------------------------------------
// Kernel D: plan-driven gather (fp32 -> bf16 LDS) + MFMA contraction.
// ---------------------------------------------------------------------------
constexpr int PPB = 64;

__global__ __launch_bounds__(256) void k_deform(const float* __restrict__ xp,
                                                const int4* __restrict__ gtabO,
                                                const float4* __restrict__ gtabW,
                                                const unsigned short* __restrict__ wA,
                                                float* __restrict__ out) {
    __shared__ __align__(16) unsigned short valT[64 * CK];   // 72 KB
    const int tid  = threadIdx.x;
    const int lane = tid & 63;
    const int wv   = tid >> 6;
    const int q    = lane >> 4;
    const int l15  = lane & 15;
    const int pix0 = blockIdx.x * PPB;
    const int bb   = pix0 / HW;
    const float* xb = xp + (size_t)bb * Hp * Wp * C;

    // ---- Phase 1: gather per plan, 4 channels/thread ----
    const int c0 = l15 * 4;
    for (int pi = 0; pi < 4; ++pi) {
        const int p_local = wv * 16 + pi * 4 + q;
        const int pix = pix0 + p_local;
        const int4*   gO = gtabO + (size_t)pix * 9;
        const float4* gW = gtabW + (size_t)pix * 9;
        int wbase = p_local * (CK * 2) + l15 * 8;
        wbase ^= (p_local & 7) << 4;
#pragma unroll
        for (int k = 0; k < 9; ++k) {
            const int4   o  = gO[k];
            const float4 wt = gW[k];
            const float4 v00 = *reinterpret_cast<const float4*>(xb + o.x + c0);
            const float4 v01 = *reinterpret_cast<const float4*>(xb + o.y + c0);
            const float4 v10 = *reinterpret_cast<const float4*>(xb + o.z + c0);
            const float4 v11 = *reinterpret_cast<const float4*>(xb + o.w + c0);
            const float s0 = wt.x * v00.x + wt.y * v01.x + wt.z * v10.x + wt.w * v11.x;
            const float s1 = wt.x * v00.y + wt.y * v01.y + wt.z * v10.y + wt.w * v11.y;
            const float s2 = wt.x * v00.z + wt.y * v01.z + wt.z * v10.z + wt.w * v11.z;
            const float s3 = wt.x * v00.w + wt.y * v01.w + wt.z * v10.w + wt.w * v11.w;
            *reinterpret_cast<uint2*>(reinterpret_cast<char*>(valT) + wbase + k * 128) =
                make_uint2(cvtpk(s0, s1), cvtpk(s2, s3));
        }
    }
    __syncthreads();

    // ---- Phase 2: MFMA GEMM ----
    f32x4 acc[4] = {{0.f,0.f,0.f,0.f},{0.f,0.f,0.f,0.f},{0.f,0.f,0.f,0.f},{0.f,0.f,0.f,0.f}};
    const unsigned short* wrow = wA + (size_t)(wv * 16 + l15) * CK;
#pragma unroll 3
    for (int ks = 0; ks < 18; ++ks) {
        const bf16x8 af = *reinterpret_cast<const bf16x8*>(wrow + ks * 32 + q * 8);
#pragma unroll
        for (int nt = 0; nt < 4; ++nt) {
            const int row = nt * 16 + l15;
            int byte = row * (CK * 2) + ks * 64 + q * 16;
            byte ^= (row & 7) << 4;
            const bf16x8 bfv = *reinterpret_cast<const bf16x8*>(
                reinterpret_cast<const char*>(valT) + byte);
            acc[nt] = __builtin_amdgcn_mfma_f32_16x16x32_bf16(af, bfv, acc[nt], 0, 0, 0);
        }
    }

    // ---- Store ----
    const int o0 = wv * 16 + q * 4;
#pragma unroll
    for (int nt = 0; nt < 4; ++nt) {
        const int pixn = pix0 + nt * 16 + l15;
        const int hw   = pixn - bb * HW;
#pragma unroll
        for (int r = 0; r < 4; ++r)
            out[((size_t)bb * COUT + o0 + r) * HW + hw] = acc[nt][r];
    }
}

// ---------------------------------------------------------------------------
extern "C" void kernel_launch(void* const* d_in, const int* in_sizes, int n_in,
                              void* d_out, int out_size, void* d_ws, size_t ws_size,
                              hipStream_t stream) {
    const float* x     = (const float*)d_in[0];
    const float* w_off = (const float*)d_in[1];
    const float* b_off = (const float*)d_in[2];
    const float* w_msk = (const float*)d_in[3];
    const float* b_msk = (const float*)d_in[4];
    const float* w_def = (const float*)d_in[5];
    float* out = (float*)d_out;

    float* ws    = (float*)d_ws;
    float* xpadT = ws;                                        // B*Hp*Wp*C floats
    int4*   gtabO = (int4*)(xpadT + (size_t)B * Hp * Wp * C); // NPIX*9 int4
    float4* gtabW = (float4*)(gtabO + (size_t)NPIX * 9);      // NPIX*9 float4
    float*  biasv = (float*)(gtabW + (size_t)NPIX * 9);       // 32 floats
    unsigned short* wA   = (unsigned short*)(biasv + 32);     // 64*576 bf16
    unsigned short* womA = wA + (size_t)COUT * CK;            // 32*576 bf16

    k_border<<<(B * 900 * 16 + 255) / 256, 256, 0, stream>>>(xpadT);
    k_padT<<<dim3(HW / 32, C / 32, B), dim3(32, 8), 0, stream>>>(x, xpadT);
    k_wA<<<(COUT * CK + 255) / 256, 256, 0, stream>>>(w_def, wA);
    k_womA<<<(32 * CK + 255) / 256, 256, 0, stream>>>(w_off, w_msk, b_off, b_msk,
                                                      womA, biasv);
    k_convom<<<NPIX / 64, 256, 0, stream>>>(xpadT, womA, biasv, gtabO, gtabW);
    k_deform<<<NPIX / PPB, 256, 0, stream>>>(xpadT, gtabO, gtabW, wA, out);
}

// Round 7
// 200.737 us; speedup vs baseline: 7.2067x; 1.0182x over previous
//
#include <hip/hip_runtime.h>
#include <hip/hip_bf16.h>
#include <math.h>

// Problem constants
constexpr int B    = 2;
constexpr int C    = 64;
constexpr int H    = 224;
constexpr int W    = 224;
constexpr int Hp   = 226;   // padded
constexpr int Wp   = 226;
constexpr int K2   = 9;
constexpr int OCO  = 18;
constexpr int OM   = 27;
constexpr int COUT = 64;
constexpr int HW   = H * W;         // 50176
constexpr int NPIX = B * HW;        // 100352
constexpr int CK   = C * K2;        // 576
constexpr int CPB  = 32;            // pixels per GEMM block

typedef short  bf16x8 __attribute__((ext_vector_type(8)));
typedef float  f32x4  __attribute__((ext_vector_type(4)));

__device__ inline unsigned short f2bf(float f) {
    union { float f; unsigned u; } v; v.f = f;
    unsigned r = v.u + 0x7FFF + ((v.u >> 16) & 1);   // RNE
    return (unsigned short)(r >> 16);
}
// packed f32x2 -> bf16x2 (low = a), via compiler cvt_pk
__device__ inline unsigned cvtpk(float a, float b) {
    __hip_bfloat162 h = __float22bfloat162_rn(make_float2(a, b));
    union { __hip_bfloat162 h; unsigned u; } cv; cv.h = h;
    return cv.u;
}
// bf16 halves of a dword -> f32
__device__ inline float blo(unsigned u) { union { unsigned u; float f; } c; c.u = u << 16; return c.f; }
__device__ inline float bhi(unsigned u) { union { unsigned u; float f; } c; c.u = u & 0xFFFF0000u; return c.f; }

// ---------------------------------------------------------------------------
// Kernel P: x NCHW fp32 -> padded NHWC bf16  xpadT[b][y+1][x+1][c]
// Block: 32 hw x 64 c. Writes uint2 (4 bf16 ch) coalesced.
// ---------------------------------------------------------------------------
__global__ __launch_bounds__(256) void k_padT(const float* __restrict__ x,
                                              unsigned short* __restrict__ xp) {
    __shared__ float tile[64][33];
    const int b   = blockIdx.y;
    const int hw0 = blockIdx.x * 32;
    const int tid = threadIdx.x;
    const int hwl = tid & 31, cl = tid >> 5;
    const float* xb = x + (size_t)b * C * HW;
#pragma unroll
    for (int j = 0; j < 8; ++j) {
        int c = cl + j * 8;
        tile[c][hwl] = xb[(size_t)c * HW + hw0 + hwl];
    }
    __syncthreads();
    unsigned short* xpb = xp + (size_t)b * Hp * Wp * C;
    const int l15 = tid & 15, hh = tid >> 4;   // hh 0..15
    const int c = l15 * 4;
    {
        int hw = hw0 + hh;                      // 32|W: block stays in one row
        int y = hw / W, xx = hw % W;
        float t0 = tile[c][hh], t1 = tile[c + 1][hh];
        float t2 = tile[c + 2][hh], t3 = tile[c + 3][hh];
        *reinterpret_cast<uint2*>(xpb + ((size_t)(y + 1) * Wp + (xx + 1)) * C + c) =
            make_uint2(cvtpk(t0, t1), cvtpk(t2, t3));
    }
    {
        int hw = hw0 + 16 + hh;
        int y = hw / W, xx = hw % W;
        float t0 = tile[c][16 + hh], t1 = tile[c + 1][16 + hh];
        float t2 = tile[c + 2][16 + hh], t3 = tile[c + 3][16 + hh];
        *reinterpret_cast<uint2*>(xpb + ((size_t)(y + 1) * Wp + (xx + 1)) * C + c) =
            make_uint2(cvtpk(t0, t1), cvtpk(t2, t3));
    }
}

// ---------------------------------------------------------------------------
// Kernel B: zero the pad border (900 cells/batch x 64 bf16 ch)
// ---------------------------------------------------------------------------
__global__ void k_border(unsigned short* __restrict__ xp) {
    int i = blockIdx.x * 256 + threadIdx.x;   // B*900*8 uint4-chunks
    if (i >= B * 900 * 8) return;
    int chunk = i & 7;
    int cell  = (i >> 3) % 900;
    int b     = (i >> 3) / 900;
    int y, x;
    if      (cell < 226) { y = 0;              x = cell; }
    else if (cell < 452) { y = Hp - 1;         x = cell - 226; }
    else if (cell < 676) { y = cell - 452 + 1; x = 0; }
    else                 { y = cell - 676 + 1; x = Wp - 1; }
    uint4 z = make_uint4(0u, 0u, 0u, 0u);
    *reinterpret_cast<uint4*>(xp + ((size_t)b * Hp * Wp + y * Wp + x) * C + chunk * 8) = z;
}

// ---------------------------------------------------------------------------
// Kernel T2: wA[o][k*64+c] = bf16(w_deform[o][c][k])
// ---------------------------------------------------------------------------
__global__ void k_wA(const float* __restrict__ wd, unsigned short* __restrict__ wA) {
    int i = blockIdx.x * 256 + threadIdx.x;
    if (i >= COUT * CK) return;
    int o  = i / CK;
    int kc = i % CK;
    int k  = kc >> 6;
    int c  = kc & 63;
    wA[i] = f2bf(wd[((size_t)o * C + c) * 9 + k]);
}

// ---------------------------------------------------------------------------
// Kernel T3: womA[oc][k*64+c] bf16 (27..31 zero) + biasv[32]
// ---------------------------------------------------------------------------
__global__ void k_womA(const float* __restrict__ w_off,
                       const float* __restrict__ w_msk,
                       const float* __restrict__ b_off,
                       const float* __restrict__ b_msk,
                       unsigned short* __restrict__ womA,
                       float* __restrict__ biasv) {
    int i = blockIdx.x * 256 + threadIdx.x;
    if (i < 32) biasv[i] = (i < OCO) ? b_off[i] : (i < OM) ? b_msk[i - OCO] : 0.f;
    if (i >= 32 * CK) return;
    int oc = i / CK;
    int kc = i % CK;
    int k  = kc >> 6;
    int c  = kc & 63;
    float v = (oc < OCO) ? w_off[((size_t)oc * C + c) * 9 + k]
            : (oc < OM)  ? w_msk[((size_t)(oc - OCO) * C + c) * 9 + k]
                         : 0.f;
    womA[i] = f2bf(v);
}

// ---------------------------------------------------------------------------
// Kernel C: offset+mask conv as MFMA GEMM + bilinear-plan epilogue.
// 32 px/block, imcol 36 KB + som 3.5 KB -> 4 blocks/CU. XCD-swizzled grid.
// ---------------------------------------------------------------------------
__global__ __launch_bounds__(256, 4) void k_convom(const unsigned short* __restrict__ xp,
                                                   const unsigned short* __restrict__ womA,
                                                   const float* __restrict__ biasv,
                                                   int4* __restrict__ gtabO,
                                                   float4* __restrict__ gtabW) {
    __shared__ __align__(16) unsigned short imcol[CPB * CK];   // 36 KB
    __shared__ float som[CPB][28];                             // 3.5 KB
    const int tid  = threadIdx.x;
    const int lane = tid & 63;
    const int wv   = tid >> 6;
    const int q    = lane >> 4;
    const int l15  = lane & 15;
    int bid = blockIdx.x;                       // nwg=3136, 3136%8==0
    bid = (bid & 7) * (gridDim.x >> 3) + (bid >> 3);
    const int pix0 = bid * CPB;
    const int bb   = pix0 / HW;                 // 32|HW: never spans batch
    const unsigned short* xb = xp + (size_t)bb * Hp * Wp * C;

    // ---- Phase 1: im2col (pure bf16 copy) ----
    const int c0 = l15 * 4;
#pragma unroll
    for (int pi = 0; pi < 2; ++pi) {
        const int p_local = pi * 16 + wv * 4 + q;
        const int pix = pix0 + p_local;
        const int hw  = pix - bb * HW;
        const int y   = hw / W;
        const int xx  = hw % W;
        int wbase = p_local * (CK * 2) + l15 * 8;
        wbase ^= (p_local & 7) << 4;
#pragma unroll
        for (int k = 0; k < 9; ++k) {
            const int ky = k / 3, kx = k % 3;
            const uint2 v = *reinterpret_cast<const uint2*>(
                xb + ((size_t)(y + ky) * Wp + (xx + kx)) * C + c0);
            *reinterpret_cast<uint2*>(reinterpret_cast<char*>(imcol) + wbase + k * 128) = v;
        }
    }
    __syncthreads();

    // ---- Phase 2: MFMA, one 16x16 tile per wave: m=wv&1 (oc), n=wv>>1 (px) ----
    f32x4 acc = {0.f, 0.f, 0.f, 0.f};
    const int m = wv & 1, n = wv >> 1;
    const unsigned short* a0 = womA + (size_t)(m * 16 + l15) * CK;
    const int row = n * 16 + l15;
#pragma unroll 3
    for (int ks = 0; ks < 18; ++ks) {
        int byte = row * (CK * 2) + ks * 64 + q * 16;
        byte ^= (row & 7) << 4;
        const bf16x8 bfv = *reinterpret_cast<const bf16x8*>(
            reinterpret_cast<const char*>(imcol) + byte);
        const bf16x8 af = *reinterpret_cast<const bf16x8*>(a0 + ks * 32 + q * 8);
        acc = __builtin_amdgcn_mfma_f32_16x16x32_bf16(af, bfv, acc, 0, 0, 0);
    }

    // ---- Epilogue A: bias/sigmoid -> som LDS ----
    {
        const int p = n * 16 + l15;
#pragma unroll
        for (int r = 0; r < 4; ++r) {
            const int oc = m * 16 + q * 4 + r;
            if (oc < OM) {
                float v = acc[r] + biasv[oc];
                som[p][oc] = (oc < OCO) ? v : 1.0f / (1.0f + __expf(-v));
            }
        }
    }
    __syncthreads();

    // ---- Epilogue B: bilinear plan per (pix,k) -> gtab ----
    for (int e = tid; e < CPB * 9; e += 256) {
        const int p  = e / 9;
        const int k  = e - p * 9;
        const int pix = pix0 + p;
        const int hw  = pix - bb * HW;
        const int ho  = hw / W;
        const int wo  = hw - ho * W;
        const int ky  = k / 3, kx = k - (k / 3) * 3;
        const float dy = som[p][2 * k];
        const float dx = som[p][2 * k + 1];
        const float mm = som[p][OCO + k];
        const float py = dy + (float)(ho + ky - 1);
        const float px = dx + (float)(wo + kx - 1);
        const float fy = floorf(py), fx = floorf(px);
        const int   y0 = (int)fy,   x0 = (int)fx;
        const float wy1 = py - fy,  wx1 = px - fx;
        const float wy0 = 1.f - wy1, wx0 = 1.f - wx1;
        const bool iy0 = (y0 >= 0) & (y0 < H);
        const bool iy1 = (y0 + 1 >= 0) & (y0 + 1 < H);
        const bool ix0 = (x0 >= 0) & (x0 < W);
        const bool ix1 = (x0 + 1 >= 0) & (x0 + 1 < W);
        const int ya = min(max(y0 + 1, 0), Hp - 1);
        const int yb = min(max(y0 + 2, 0), Hp - 1);
        const int xa = min(max(x0 + 1, 0), Wp - 1);
        const int xc = min(max(x0 + 2, 0), Wp - 1);
        const int rA = ya * Wp, rB = yb * Wp;
        gtabO[(size_t)pix * 9 + k] = make_int4((rA + xa) * C, (rA + xc) * C,
                                               (rB + xa) * C, (rB + xc) * C);
        gtabW[(size_t)pix * 9 + k] = make_float4(
            wy0 * wx0 * mm * ((iy0 & ix0) ? 1.f : 0.f),
            wy0 * wx1 * mm * ((iy0 & ix1) ? 1.f : 0.f),
            wy1 * wx0 * mm * ((iy1 & ix0) ? 1.f : 0.f),
            wy1 * wx1 * mm * ((iy1 & ix1) ? 1.f : 0.f));
    }
}

// ---------------------------------------------------------------------------
// Kernel D: plan-driven bf16 gather + MFMA contraction.
// 32 px/block, 36 KB LDS -> 4 blocks/CU. XCD-swizzled grid.
// ---------------------------------------------------------------------------
__global__ __launch_bounds__(256, 4) void k_deform(const unsigned short* __restrict__ xp,
                                                   const int4* __restrict__ gtabO,
                                                   const float4* __restrict__ gtabW,
                                                   const unsigned short* __restrict__ wA,
                                                   float* __restrict__ out) {
    __shared__ __align__(16) unsigned short valT[CPB * CK];   // 36 KB
    const int tid  = threadIdx.x;
    const int lane = tid & 63;
    const int wv   = tid >> 6;
    const int q    = lane >> 4;
    const int l15  = lane & 15;
    int bid = blockIdx.x;
    bid = (bid & 7) * (gridDim.x >> 3) + (bid >> 3);
    const int pix0 = bid * CPB;
    const int bb   = pix0 / HW;
    const unsigned short* xb = xp + (size_t)bb * Hp * Wp * C;

    // ---- Phase 1: gather per plan, 4 bf16 channels/thread ----
    const int c0 = l15 * 4;
#pragma unroll
    for (int pi = 0; pi < 2; ++pi) {
        const int p_local = pi * 16 + wv * 4 + q;
        const int pix = pix0 + p_local;
        const int4*   gO = gtabO + (size_t)pix * 9;
        const float4* gW = gtabW + (size_t)pix * 9;
        int wbase = p_local * (CK * 2) + l15 * 8;
        wbase ^= (p_local & 7) << 4;
#pragma unroll
        for (int k = 0; k < 9; ++k) {
            const int4   o  = gO[k];
            const float4 wt = gW[k];
            const uint2 u00 = *reinterpret_cast<const uint2*>(xb + o.x + c0);
            const uint2 u01 = *reinterpret_cast<const uint2*>(xb + o.y + c0);
            const uint2 u10 = *reinterpret_cast<const uint2*>(xb + o.z + c0);
            const uint2 u11 = *reinterpret_cast<const uint2*>(xb + o.w + c0);
            const float s0 = wt.x * blo(u00.x) + wt.y * blo(u01.x) + wt.z * blo(u10.x) + wt.w * blo(u11.x);
            const float s1 = wt.x * bhi(u00.x) + wt.y * bhi(u01.x) + wt.z * bhi(u10.x) + wt.w * bhi(u11.x);
            const float s2 = wt.x * blo(u00.y) + wt.y * blo(u01.y) + wt.z * blo(u10.y) + wt.w * blo(u11.y);
            const float s3 = wt.x * bhi(u00.y) + wt.y * bhi(u01.y) + wt.z * bhi(u10.y) + wt.w * bhi(u11.y);
            *reinterpret_cast<uint2*>(reinterpret_cast<char*>(valT) + wbase + k * 128) =
                make_uint2(cvtpk(s0, s1), cvtpk(s2, s3));
        }
    }
    __syncthreads();

    // ---- Phase 2: MFMA GEMM: wave = 16 o-rows x 32 px (2 n-tiles) ----
    f32x4 acc[2] = {{0.f,0.f,0.f,0.f},{0.f,0.f,0.f,0.f}};
    const unsigned short* wrow = wA + (size_t)(wv * 16 + l15) * CK;
#pragma unroll 3
    for (int ks = 0; ks < 18; ++ks) {
        const bf16x8 af = *reinterpret_cast<const bf16x8*>(wrow + ks * 32 + q * 8);
#pragma unroll
        for (int nt = 0; nt < 2; ++nt) {
            const int row = nt * 16 + l15;
            int byte = row * (CK * 2) + ks * 64 + q * 16;
            byte ^= (row & 7) << 4;
            const bf16x8 bfv = *reinterpret_cast<const bf16x8*>(
                reinterpret_cast<const char*>(valT) + byte);
            acc[nt] = __builtin_amdgcn_mfma_f32_16x16x32_bf16(af, bfv, acc[nt], 0, 0, 0);
        }
    }

    // ---- Store ----
    const int o0 = wv * 16 + q * 4;
#pragma unroll
    for (int nt = 0; nt < 2; ++nt) {
        const int pixn = pix0 + nt * 16 + l15;
        const int hw   = pixn - bb * HW;
#pragma unroll
        for (int r = 0; r < 4; ++r)
            out[((size_t)bb * COUT + o0 + r) * HW + hw] = acc[nt][r];
    }
}

// ---------------------------------------------------------------------------
extern "C" void kernel_launch(void* const* d_in, const int* in_sizes, int n_in,
                              void* d_out, int out_size, void* d_ws, size_t ws_size,
                              hipStream_t stream) {
    const float* x     = (const float*)d_in[0];
    const float* w_off = (const float*)d_in[1];
    const float* b_off = (const float*)d_in[2];
    const float* w_msk = (const float*)d_in[3];
    const float* b_msk = (const float*)d_in[4];
    const float* w_def = (const float*)d_in[5];
    float* out = (float*)d_out;

    unsigned short* xpadT = (unsigned short*)d_ws;            // B*Hp*Wp*C bf16
    int4*   gtabO = (int4*)(xpadT + (size_t)B * Hp * Wp * C); // NPIX*9 int4
    float4* gtabW = (float4*)(gtabO + (size_t)NPIX * 9);      // NPIX*9 float4
    float*  biasv = (float*)(gtabW + (size_t)NPIX * 9);       // 32 floats
    unsigned short* wA   = (unsigned short*)(biasv + 32);     // 64*576 bf16
    unsigned short* womA = wA + (size_t)COUT * CK;            // 32*576 bf16

    k_border<<<(B * 900 * 8 + 255) / 256, 256, 0, stream>>>(xpadT);
    k_padT<<<dim3(HW / 32, B), 256, 0, stream>>>(x, xpadT);
    k_wA<<<(COUT * CK + 255) / 256, 256, 0, stream>>>(w_def, wA);
    k_womA<<<(32 * CK + 255) / 256, 256, 0, stream>>>(w_off, w_msk, b_off, b_msk,
                                                      womA, biasv);
    k_convom<<<NPIX / CPB, 256, 0, stream>>>(xpadT, womA, biasv, gtabO, gtabW);
    k_deform<<<NPIX / CPB, 256, 0, stream>>>(xpadT, gtabO, gtabW, wA, out);
}

// Round 9
// 183.809 us; speedup vs baseline: 7.8704x; 1.0921x over previous
//
#include <hip/hip_runtime.h>
#include <hip/hip_bf16.h>
#include <math.h>

// Problem constants
constexpr int B    = 2;
constexpr int C    = 64;
constexpr int H    = 224;
constexpr int W    = 224;
constexpr int Hp   = 226;   // padded
constexpr int Wp   = 226;
constexpr int OCO  = 18;
constexpr int OM   = 27;
constexpr int COUT = 64;
constexpr int HW   = H * W;         // 50176
constexpr int NPIX = B * HW;        // 100352
constexpr int CK   = C * 9;         // 576
constexpr int CPB  = 32;            // pixels per fused block

typedef short  bf16x8 __attribute__((ext_vector_type(8)));
typedef float  f32x4  __attribute__((ext_vector_type(4)));

__device__ inline unsigned short f2bf(float f) {
    union { float f; unsigned u; } v; v.f = f;
    unsigned r = v.u + 0x7FFF + ((v.u >> 16) & 1);   // RNE
    return (unsigned short)(r >> 16);
}
__device__ inline unsigned cvtpk(float a, float b) {
    __hip_bfloat162 h = __float22bfloat162_rn(make_float2(a, b));
    union { __hip_bfloat162 h; unsigned u; } cv; cv.h = h;
    return cv.u;
}
__device__ inline float blo(unsigned u) { union { unsigned u; float f; } c; c.u = u << 16; return c.f; }
__device__ inline float bhi(unsigned u) { union { unsigned u; float f; } c; c.u = u & 0xFFFF0000u; return c.f; }

// ---------------------------------------------------------------------------
// Kernel P: x NCHW fp32 -> padded NHWC bf16  xpadT[b][y+1][x+1][c]
// ---------------------------------------------------------------------------
__global__ __launch_bounds__(256) void k_padT(const float* __restrict__ x,
                                              unsigned short* __restrict__ xp) {
    __shared__ float tile[64][33];
    const int b   = blockIdx.y;
    const int hw0 = blockIdx.x * 32;
    const int tid = threadIdx.x;
    const int hwl = tid & 31, cl = tid >> 5;
    const float* xb = x + (size_t)b * C * HW;
#pragma unroll
    for (int j = 0; j < 8; ++j) {
        int c = cl + j * 8;
        tile[c][hwl] = xb[(size_t)c * HW + hw0 + hwl];
    }
    __syncthreads();
    unsigned short* xpb = xp + (size_t)b * Hp * Wp * C;
    const int l15 = tid & 15, hh = tid >> 4;
    const int c = l15 * 4;
#pragma unroll
    for (int half = 0; half < 2; ++half) {
        int hw = hw0 + half * 16 + hh;          // 32|W: stays in one image row
        int y = hw / W, xx = hw % W;
        float t0 = tile[c][half * 16 + hh],     t1 = tile[c + 1][half * 16 + hh];
        float t2 = tile[c + 2][half * 16 + hh], t3 = tile[c + 3][half * 16 + hh];
        *reinterpret_cast<uint2*>(xpb + ((size_t)(y + 1) * Wp + (xx + 1)) * C + c) =
            make_uint2(cvtpk(t0, t1), cvtpk(t2, t3));
    }
}

// ---------------------------------------------------------------------------
// Kernel B: zero the pad border
// ---------------------------------------------------------------------------
__global__ void k_border(unsigned short* __restrict__ xp) {
    int i = blockIdx.x * 256 + threadIdx.x;   // B*900*8 uint4-chunks
    if (i >= B * 900 * 8) return;
    int chunk = i & 7;
    int cell  = (i >> 3) % 900;
    int b     = (i >> 3) / 900;
    int y, x;
    if      (cell < 226) { y = 0;              x = cell; }
    else if (cell < 452) { y = Hp - 1;         x = cell - 226; }
    else if (cell < 676) { y = cell - 452 + 1; x = 0; }
    else                 { y = cell - 676 + 1; x = Wp - 1; }
    uint4 z = make_uint4(0u, 0u, 0u, 0u);
    *reinterpret_cast<uint4*>(xp + ((size_t)b * Hp * Wp + y * Wp + x) * C + chunk * 8) = z;
}

// ---------------------------------------------------------------------------
// Kernel T2: wA[o][k*64+c] = bf16(w_deform[o][c][k])
// ---------------------------------------------------------------------------
__global__ void k_wA(const float* __restrict__ wd, unsigned short* __restrict__ wA) {
    int i = blockIdx.x * 256 + threadIdx.x;
    if (i >= COUT * CK) return;
    int o  = i / CK;
    int kc = i % CK;
    int k  = kc >> 6;
    int c  = kc & 63;
    wA[i] = f2bf(wd[((size_t)o * C + c) * 9 + k]);
}

// ---------------------------------------------------------------------------
// Kernel T3: womA[oc][k*64+c] bf16 (27..31 zero) + biasv[32]
// ---------------------------------------------------------------------------
__global__ void k_womA(const float* __restrict__ w_off,
                       const float* __restrict__ w_msk,
                       const float* __restrict__ b_off,
                       const float* __restrict__ b_msk,
                       unsigned short* __restrict__ womA,
                       float* __restrict__ biasv) {
    int i = blockIdx.x * 256 + threadIdx.x;
    if (i < 32) biasv[i] = (i < OCO) ? b_off[i] : (i < OM) ? b_msk[i - OCO] : 0.f;
    if (i >= 32 * CK) return;
    int oc = i / CK;
    int kc = i % CK;
    int k  = kc >> 6;
    int c  = kc & 63;
    float v = (oc < OCO) ? w_off[((size_t)oc * C + c) * 9 + k]
            : (oc < OM)  ? w_msk[((size_t)(oc - OCO) * C + c) * 9 + k]
                         : 0.f;
    womA[i] = f2bf(v);
}

// ---------------------------------------------------------------------------
// Fused kernel — phases A..E are VERBATIM round-7 kernel bodies; the only
// change is the plan lives in typed LDS arrays instead of global gtab.
//   A: im2col -> imcol LDS (bf16, XOR-swizzled)       [r7 k_convom phase 1]
//   B: GEMM1 -> som LDS                               [r7 k_convom phase 2]
//   C: bilinear plan -> gplanO/gplanW LDS             [r7 k_convom epilogue B]
//   D: gather per plan -> imcol (valT)                [r7 k_deform phase 1]
//   E: GEMM2 -> out                                   [r7 k_deform phase 2]
// LDS: 36864 + 3584 + 4608 + 4608 = 49664 B -> 3 blocks/CU.
// ---------------------------------------------------------------------------
__global__ __launch_bounds__(256, 3) void k_fused(const unsigned short* __restrict__ xp,
                                                  const unsigned short* __restrict__ womA,
                                                  const unsigned short* __restrict__ wA,
                                                  const float* __restrict__ biasv,
                                                  float* __restrict__ out) {
    __shared__ __align__(16) unsigned short imcol[CPB * CK];   // 36864 B (also valT)
    __shared__ float som[CPB][28];                             // 3584 B
    __shared__ int4   gplanO[CPB * 9];                         // 4608 B
    __shared__ float4 gplanW[CPB * 9];                         // 4608 B
    const int tid  = threadIdx.x;
    const int lane = tid & 63;
    const int wv   = tid >> 6;
    const int q    = lane >> 4;
    const int l15  = lane & 15;
    int bid = blockIdx.x;                        // nwg=3136, 3136%8==0
    bid = (bid & 7) * (gridDim.x >> 3) + (bid >> 3);
    const int pix0 = bid * CPB;
    const int bb   = pix0 / HW;                  // 32|HW: never spans batch
    const unsigned short* xb = xp + (size_t)bb * Hp * Wp * C;

    const int c0 = l15 * 4;

    // ---- Phase A: im2col (bf16 copy), r7 mapping: 2 px per (wv,q), 4 ch ----
#pragma unroll
    for (int pi = 0; pi < 2; ++pi) {
        const int p_local = pi * 16 + wv * 4 + q;
        const int pix = pix0 + p_local;
        const int hw  = pix - bb * HW;
        const int y   = hw / W;
        const int xx  = hw % W;
        int wbase = p_local * (CK * 2) + l15 * 8;
        wbase ^= (p_local & 7) << 4;
#pragma unroll
        for (int k = 0; k < 9; ++k) {
            const int ky = k / 3, kx = k % 3;
            const uint2 v = *reinterpret_cast<const uint2*>(
                xb + ((size_t)(y + ky) * Wp + (xx + kx)) * C + c0);
            *reinterpret_cast<uint2*>(reinterpret_cast<char*>(imcol) + wbase + k * 128) = v;
        }
    }
    __syncthreads();

    // ---- Phase B: GEMM1, one 16x16 tile per wave: m=wv&1 (oc), n=wv>>1 (px) ----
    {
        f32x4 acc = {0.f, 0.f, 0.f, 0.f};
        const int m = wv & 1, n = wv >> 1;
        const unsigned short* a0 = womA + (size_t)(m * 16 + l15) * CK;
        const int row = n * 16 + l15;
#pragma unroll 3
        for (int ks = 0; ks < 18; ++ks) {
            int byte = row * (CK * 2) + ks * 64 + q * 16;
            byte ^= (row & 7) << 4;
            const bf16x8 bfv = *reinterpret_cast<const bf16x8*>(
                reinterpret_cast<const char*>(imcol) + byte);
            const bf16x8 af = *reinterpret_cast<const bf16x8*>(a0 + ks * 32 + q * 8);
            acc = __builtin_amdgcn_mfma_f32_16x16x32_bf16(af, bfv, acc, 0, 0, 0);
        }
        const int pp = n * 16 + l15;
#pragma unroll
        for (int r = 0; r < 4; ++r) {
            const int oc = m * 16 + q * 4 + r;
            if (oc < OM) {
                float v = acc[r] + biasv[oc];
                som[pp][oc] = (oc < OCO) ? v : 1.0f / (1.0f + __expf(-v));
            }
        }
    }
    __syncthreads();

    // ---- Phase C: bilinear plan -> gplanO/gplanW (typed LDS) ----
    for (int e = tid; e < CPB * 9; e += 256) {
        const int pe = e / 9;
        const int k  = e - pe * 9;
        const int pix = pix0 + pe;
        const int hw  = pix - bb * HW;
        const int ho  = hw / W;
        const int wo  = hw - ho * W;
        const int ky  = k / 3, kx = k - (k / 3) * 3;
        const float dy = som[pe][2 * k];
        const float dx = som[pe][2 * k + 1];
        const float mm = som[pe][OCO + k];
        const float py = dy + (float)(ho + ky - 1);
        const float px = dx + (float)(wo + kx - 1);
        const float fy = floorf(py), fx = floorf(px);
        const int   y0 = (int)fy,   x0 = (int)fx;
        const float wy1 = py - fy,  wx1 = px - fx;
        const float wy0 = 1.f - wy1, wx0 = 1.f - wx1;
        const bool iy0 = (y0 >= 0) & (y0 < H);
        const bool iy1 = (y0 + 1 >= 0) & (y0 + 1 < H);
        const bool ix0 = (x0 >= 0) & (x0 < W);
        const bool ix1 = (x0 + 1 >= 0) & (x0 + 1 < W);
        const int ya = min(max(y0 + 1, 0), Hp - 1);
        const int yb = min(max(y0 + 2, 0), Hp - 1);
        const int xa = min(max(x0 + 1, 0), Wp - 1);
        const int xc = min(max(x0 + 2, 0), Wp - 1);
        const int rA = ya * Wp, rB = yb * Wp;
        gplanO[e] = make_int4((rA + xa) * C, (rA + xc) * C,
                              (rB + xa) * C, (rB + xc) * C);
        gplanW[e] = make_float4(
            wy0 * wx0 * mm * ((iy0 & ix0) ? 1.f : 0.f),
            wy0 * wx1 * mm * ((iy0 & ix1) ? 1.f : 0.f),
            wy1 * wx0 * mm * ((iy1 & ix0) ? 1.f : 0.f),
            wy1 * wx1 * mm * ((iy1 & ix1) ? 1.f : 0.f));
    }
    __syncthreads();

    // ---- Phase D: gather per plan (r7 mapping: 2 px per (wv,q), 4 ch) ----
#pragma unroll
    for (int pi = 0; pi < 2; ++pi) {
        const int p_local = pi * 16 + wv * 4 + q;
        int wbase = p_local * (CK * 2) + l15 * 8;
        wbase ^= (p_local & 7) << 4;
#pragma unroll
        for (int k = 0; k < 9; ++k) {
            const int4   o  = gplanO[p_local * 9 + k];
            const float4 wt = gplanW[p_local * 9 + k];
            const uint2 u00 = *reinterpret_cast<const uint2*>(xb + o.x + c0);
            const uint2 u01 = *reinterpret_cast<const uint2*>(xb + o.y + c0);
            const uint2 u10 = *reinterpret_cast<const uint2*>(xb + o.z + c0);
            const uint2 u11 = *reinterpret_cast<const uint2*>(xb + o.w + c0);
            const float s0 = wt.x * blo(u00.x) + wt.y * blo(u01.x) + wt.z * blo(u10.x) + wt.w * blo(u11.x);
            const float s1 = wt.x * bhi(u00.x) + wt.y * bhi(u01.x) + wt.z * bhi(u10.x) + wt.w * bhi(u11.x);
            const float s2 = wt.x * blo(u00.y) + wt.y * blo(u01.y) + wt.z * blo(u10.y) + wt.w * blo(u11.y);
            const float s3 = wt.x * bhi(u00.y) + wt.y * bhi(u01.y) + wt.z * bhi(u10.y) + wt.w * bhi(u11.y);
            *reinterpret_cast<uint2*>(reinterpret_cast<char*>(imcol) + wbase + k * 128) =
                make_uint2(cvtpk(s0, s1), cvtpk(s2, s3));
        }
    }
    __syncthreads();

    // ---- Phase E: GEMM2, wave = 16 o-rows x 32 px (2 n-tiles) ----
    f32x4 acc[2] = {{0.f,0.f,0.f,0.f},{0.f,0.f,0.f,0.f}};
    const unsigned short* wrow = wA + (size_t)(wv * 16 + l15) * CK;
#pragma unroll 3
    for (int ks = 0; ks < 18; ++ks) {
        const bf16x8 af = *reinterpret_cast<const bf16x8*>(wrow + ks * 32 + q * 8);
#pragma unroll
        for (int nt = 0; nt < 2; ++nt) {
            const int row = nt * 16 + l15;
            int byte = row * (CK * 2) + ks * 64 + q * 16;
            byte ^= (row & 7) << 4;
            const bf16x8 bfv = *reinterpret_cast<const bf16x8*>(
                reinterpret_cast<const char*>(imcol) + byte);
            acc[nt] = __builtin_amdgcn_mfma_f32_16x16x32_bf16(af, bfv, acc[nt], 0, 0, 0);
        }
    }

    // ---- Store ----
    const int o0 = wv * 16 + q * 4;
#pragma unroll
    for (int nt = 0; nt < 2; ++nt) {
        const int pixn = pix0 + nt * 16 + l15;
        const int hw   = pixn - bb * HW;
#pragma unroll
        for (int r = 0; r < 4; ++r)
            out[((size_t)bb * COUT + o0 + r) * HW + hw] = acc[nt][r];
    }
}

// ---------------------------------------------------------------------------
extern "C" void kernel_launch(void* const* d_in, const int* in_sizes, int n_in,
                              void* d_out, int out_size, void* d_ws, size_t ws_size,
                              hipStream_t stream) {
    const float* x     = (const float*)d_in[0];
    const float* w_off = (const float*)d_in[1];
    const float* b_off = (const float*)d_in[2];
    const float* w_msk = (const float*)d_in[3];
    const float* b_msk = (const float*)d_in[4];
    const float* w_def = (const float*)d_in[5];
    float* out = (float*)d_out;

    unsigned short* xpadT = (unsigned short*)d_ws;            // B*Hp*Wp*C bf16
    float* biasv = (float*)(xpadT + (size_t)B * Hp * Wp * C); // 32 floats
    unsigned short* wA   = (unsigned short*)(biasv + 32);     // 64*576 bf16
    unsigned short* womA = wA + (size_t)COUT * CK;            // 32*576 bf16

    k_border<<<(B * 900 * 8 + 255) / 256, 256, 0, stream>>>(xpadT);
    k_padT<<<dim3(HW / 32, B), 256, 0, stream>>>(x, xpadT);
    k_wA<<<(COUT * CK + 255) / 256, 256, 0, stream>>>(w_def, wA);
    k_womA<<<(32 * CK + 255) / 256, 256, 0, stream>>>(w_off, w_msk, b_off, b_msk,
                                                      womA, biasv);
    k_fused<<<NPIX / CPB, 256, 0, stream>>>(xpadT, womA, wA, biasv, out);
}

// Round 11
// 177.120 us; speedup vs baseline: 8.1676x; 1.0378x over previous
//
#include <hip/hip_runtime.h>
#include <hip/hip_bf16.h>
#include <math.h>

// Problem constants
constexpr int B    = 2;
constexpr int C    = 64;
constexpr int H    = 224;
constexpr int W    = 224;
constexpr int Hp   = 226;   // padded
constexpr int Wp   = 226;
constexpr int OCO  = 18;
constexpr int OM   = 27;
constexpr int COUT = 64;
constexpr int HW   = H * W;         // 50176
constexpr int NPIX = B * HW;        // 100352
constexpr int CK   = C * 9;         // 576
constexpr int CPB  = 32;            // pixels per fused block

// k_prep sub-grid ranges
constexpr int PAD_BLKS = (HW / 32) * B;          // 3136
constexpr int BOR_N    = B * 900 * 8;            // 14400 border uint4-chunks
constexpr int BOR_BLKS = (BOR_N + 255) / 256;    // 57
constexpr int WA_BLKS  = (COUT * CK) / 256;      // 144
constexpr int WOM_BLKS = (32 * CK) / 256;        // 72

typedef short  bf16x8 __attribute__((ext_vector_type(8)));
typedef float  f32x4  __attribute__((ext_vector_type(4)));

__device__ inline unsigned short f2bf(float f) {
    union { float f; unsigned u; } v; v.f = f;
    unsigned r = v.u + 0x7FFF + ((v.u >> 16) & 1);   // RNE
    return (unsigned short)(r >> 16);
}
__device__ inline unsigned cvtpk(float a, float b) {
    __hip_bfloat162 h = __float22bfloat162_rn(make_float2(a, b));
    union { __hip_bfloat162 h; unsigned u; } cv; cv.h = h;
    return cv.u;
}
__device__ inline float blo(unsigned u) { union { unsigned u; float f; } c; c.u = u << 16; return c.f; }
__device__ inline float bhi(unsigned u) { union { unsigned u; float f; } c; c.u = u & 0xFFFF0000u; return c.f; }

// ---------------------------------------------------------------------------
// Kernel PREP: one launch for all preprocessing (independent sub-jobs):
//  [0, PAD_BLKS)                 : x NCHW fp32 -> padded NHWC bf16 (interior)
//  [.., +BOR_BLKS)               : zero pad border
//  [.., +WA_BLKS)                : wA[o][k*64+c] = bf16(w_deform[o][c][k])
//  [.., +WOM_BLKS)               : womA[oc][k*64+c] bf16 + biasv[32]
// ---------------------------------------------------------------------------
__global__ __launch_bounds__(256) void k_prep(const float* __restrict__ x,
                                              unsigned short* __restrict__ xp,
                                              const float* __restrict__ wd,
                                              unsigned short* __restrict__ wA,
                                              const float* __restrict__ w_off,
                                              const float* __restrict__ w_msk,
                                              const float* __restrict__ b_off,
                                              const float* __restrict__ b_msk,
                                              unsigned short* __restrict__ womA,
                                              float* __restrict__ biasv) {
    __shared__ float tile[64][33];
    const int bx  = blockIdx.x;
    const int tid = threadIdx.x;

    if (bx < PAD_BLKS) {
        // ---- padT ----
        const int b   = bx / (HW / 32);
        const int hw0 = (bx % (HW / 32)) * 32;
        const int hwl = tid & 31, cl = tid >> 5;
        const float* xb = x + (size_t)b * C * HW;
#pragma unroll
        for (int j = 0; j < 8; ++j) {
            int c = cl + j * 8;
            tile[c][hwl] = xb[(size_t)c * HW + hw0 + hwl];
        }
        __syncthreads();
        unsigned short* xpb = xp + (size_t)b * Hp * Wp * C;
        const int l15 = tid & 15, hh = tid >> 4;
        const int c = l15 * 4;
#pragma unroll
        for (int half = 0; half < 2; ++half) {
            int hw = hw0 + half * 16 + hh;      // 32|W: stays in one image row
            int y = hw / W, xx = hw % W;
            float t0 = tile[c][half * 16 + hh],     t1 = tile[c + 1][half * 16 + hh];
            float t2 = tile[c + 2][half * 16 + hh], t3 = tile[c + 3][half * 16 + hh];
            *reinterpret_cast<uint2*>(xpb + ((size_t)(y + 1) * Wp + (xx + 1)) * C + c) =
                make_uint2(cvtpk(t0, t1), cvtpk(t2, t3));
        }
        return;
    }
    if (bx < PAD_BLKS + BOR_BLKS) {
        // ---- border zero ----
        int i = (bx - PAD_BLKS) * 256 + tid;
        if (i >= BOR_N) return;
        int chunk = i & 7;
        int cell  = (i >> 3) % 900;
        int b     = (i >> 3) / 900;
        int y, xx;
        if      (cell < 226) { y = 0;              xx = cell; }
        else if (cell < 452) { y = Hp - 1;         xx = cell - 226; }
        else if (cell < 676) { y = cell - 452 + 1; xx = 0; }
        else                 { y = cell - 676 + 1; xx = Wp - 1; }
        uint4 z = make_uint4(0u, 0u, 0u, 0u);
        *reinterpret_cast<uint4*>(xp + ((size_t)b * Hp * Wp + y * Wp + xx) * C + chunk * 8) = z;
        return;
    }
    if (bx < PAD_BLKS + BOR_BLKS + WA_BLKS) {
        // ---- wA ----
        int i  = (bx - PAD_BLKS - BOR_BLKS) * 256 + tid;   // < 36864
        int o  = i / CK;
        int kc = i % CK;
        int k  = kc >> 6;
        int c  = kc & 63;
        wA[i] = f2bf(wd[((size_t)o * C + c) * 9 + k]);
        return;
    }
    {
        // ---- womA + biasv ----
        int i = (bx - PAD_BLKS - BOR_BLKS - WA_BLKS) * 256 + tid;   // < 18432
        if (i < 32) biasv[i] = (i < OCO) ? b_off[i] : (i < OM) ? b_msk[i - OCO] : 0.f;
        int oc = i / CK;
        int kc = i % CK;
        int k  = kc >> 6;
        int c  = kc & 63;
        float v = (oc < OCO) ? w_off[((size_t)oc * C + c) * 9 + k]
                : (oc < OM)  ? w_msk[((size_t)(oc - OCO) * C + c) * 9 + k]
                             : 0.f;
        womA[i] = f2bf(v);
    }
}

// ---------------------------------------------------------------------------
// Fused kernel (phases identical in math to round 9; phase A/D restructured
// for batched load issue = ILP, rule #20-safe static indexing throughout):
//   A: im2col -> imcol LDS (bf16, XOR-swizzled)
//   B: GEMM1 -> som LDS
//   C: bilinear plan -> gplanO/gplanW LDS
//   D: gather per plan -> imcol (valT)
//   E: GEMM2 -> out
// LDS: 36864 + 3584 + 4608 + 4608 = 49664 B -> 3 blocks/CU.
// ---------------------------------------------------------------------------
__global__ __launch_bounds__(256, 3) void k_fused(const unsigned short* __restrict__ xp,
                                                  const unsigned short* __restrict__ womA,
                                                  const unsigned short* __restrict__ wA,
                                                  const float* __restrict__ biasv,
                                                  float* __restrict__ out) {
    __shared__ __align__(16) unsigned short imcol[CPB * CK];   // 36864 B (also valT)
    __shared__ float som[CPB][28];                             // 3584 B
    __shared__ int4   gplanO[CPB * 9];                         // 4608 B
    __shared__ float4 gplanW[CPB * 9];                         // 4608 B
    const int tid  = threadIdx.x;
    const int lane = tid & 63;
    const int wv   = tid >> 6;
    const int q    = lane >> 4;
    const int l15  = lane & 15;
    int bid = blockIdx.x;                        // nwg=3136, 3136%8==0
    bid = (bid & 7) * (gridDim.x >> 3) + (bid >> 3);
    const int pix0 = bid * CPB;
    const int bb   = pix0 / HW;                  // 32|HW: never spans batch
    const unsigned short* xb = xp + (size_t)bb * Hp * Wp * C;

    const int c0 = l15 * 4;

    // ---- Phase A: im2col (bf16 copy) — batched loads then writes ----
    {
        uint2 va[2][9];
#pragma unroll
        for (int pi = 0; pi < 2; ++pi) {
            const int p_local = pi * 16 + wv * 4 + q;
            const int pix = pix0 + p_local;
            const int hw  = pix - bb * HW;
            const int y   = hw / W;
            const int xx  = hw % W;
#pragma unroll
            for (int k = 0; k < 9; ++k) {
                const int ky = k / 3, kx = k % 3;
                va[pi][k] = *reinterpret_cast<const uint2*>(
                    xb + ((size_t)(y + ky) * Wp + (xx + kx)) * C + c0);
            }
        }
#pragma unroll
        for (int pi = 0; pi < 2; ++pi) {
            const int p_local = pi * 16 + wv * 4 + q;
            int wbase = p_local * (CK * 2) + l15 * 8;
            wbase ^= (p_local & 7) << 4;
#pragma unroll
            for (int k = 0; k < 9; ++k)
                *reinterpret_cast<uint2*>(reinterpret_cast<char*>(imcol) + wbase + k * 128) = va[pi][k];
        }
    }
    __syncthreads();

    // ---- Phase B: GEMM1, one 16x16 tile per wave: m=wv&1 (oc), n=wv>>1 (px) ----
    {
        f32x4 acc = {0.f, 0.f, 0.f, 0.f};
        const int m = wv & 1, n = wv >> 1;
        const unsigned short* a0 = womA + (size_t)(m * 16 + l15) * CK;
        const int row = n * 16 + l15;
#pragma unroll 3
        for (int ks = 0; ks < 18; ++ks) {
            int byte = row * (CK * 2) + ks * 64 + q * 16;
            byte ^= (row & 7) << 4;
            const bf16x8 bfv = *reinterpret_cast<const bf16x8*>(
                reinterpret_cast<const char*>(imcol) + byte);
            const bf16x8 af = *reinterpret_cast<const bf16x8*>(a0 + ks * 32 + q * 8);
            acc = __builtin_amdgcn_mfma_f32_16x16x32_bf16(af, bfv, acc, 0, 0, 0);
        }
        const int pp = n * 16 + l15;
#pragma unroll
        for (int r = 0; r < 4; ++r) {
            const int oc = m * 16 + q * 4 + r;
            if (oc < OM) {
                float v = acc[r] + biasv[oc];
                som[pp][oc] = (oc < OCO) ? v : 1.0f / (1.0f + __expf(-v));
            }
        }
    }
    __syncthreads();

    // ---- Phase C: bilinear plan -> gplanO/gplanW (typed LDS) ----
    for (int e = tid; e < CPB * 9; e += 256) {
        const int pe = e / 9;
        const int k  = e - pe * 9;
        const int pix = pix0 + pe;
        const int hw  = pix - bb * HW;
        const int ho  = hw / W;
        const int wo  = hw - ho * W;
        const int ky  = k / 3, kx = k - (k / 3) * 3;
        const float dy = som[pe][2 * k];
        const float dx = som[pe][2 * k + 1];
        const float mm = som[pe][OCO + k];
        const float py = dy + (float)(ho + ky - 1);
        const float px = dx + (float)(wo + kx - 1);
        const float fy = floorf(py), fx = floorf(px);
        const int   y0 = (int)fy,   x0 = (int)fx;
        const float wy1 = py - fy,  wx1 = px - fx;
        const float wy0 = 1.f - wy1, wx0 = 1.f - wx1;
        const bool iy0 = (y0 >= 0) & (y0 < H);
        const bool iy1 = (y0 + 1 >= 0) & (y0 + 1 < H);
        const bool ix0 = (x0 >= 0) & (x0 < W);
        const bool ix1 = (x0 + 1 >= 0) & (x0 + 1 < W);
        const int ya = min(max(y0 + 1, 0), Hp - 1);
        const int yb = min(max(y0 + 2, 0), Hp - 1);
        const int xa = min(max(x0 + 1, 0), Wp - 1);
        const int xc = min(max(x0 + 2, 0), Wp - 1);
        const int rA = ya * Wp, rB = yb * Wp;
        gplanO[e] = make_int4((rA + xa) * C, (rA + xc) * C,
                              (rB + xa) * C, (rB + xc) * C);
        gplanW[e] = make_float4(
            wy0 * wx0 * mm * ((iy0 & ix0) ? 1.f : 0.f),
            wy0 * wx1 * mm * ((iy0 & ix1) ? 1.f : 0.f),
            wy1 * wx0 * mm * ((iy1 & ix0) ? 1.f : 0.f),
            wy1 * wx1 * mm * ((iy1 & ix1) ? 1.f : 0.f));
    }
    __syncthreads();

    // ---- Phase D: gather per plan — preload plans, batch all 36 loads ----
#pragma unroll
    for (int pi = 0; pi < 2; ++pi) {
        const int p_local = pi * 16 + wv * 4 + q;
        int wbase = p_local * (CK * 2) + l15 * 8;
        wbase ^= (p_local & 7) << 4;
        int4   po[9];
        float4 pw[9];
#pragma unroll
        for (int k = 0; k < 9; ++k) {
            po[k] = gplanO[p_local * 9 + k];
            pw[k] = gplanW[p_local * 9 + k];
        }
        uint2 u00[9], u01[9], u10[9], u11[9];
#pragma unroll
        for (int k = 0; k < 9; ++k) {
            u00[k] = *reinterpret_cast<const uint2*>(xb + po[k].x + c0);
            u01[k] = *reinterpret_cast<const uint2*>(xb + po[k].y + c0);
            u10[k] = *reinterpret_cast<const uint2*>(xb + po[k].z + c0);
            u11[k] = *reinterpret_cast<const uint2*>(xb + po[k].w + c0);
        }
#pragma unroll
        for (int k = 0; k < 9; ++k) {
            const float4 wt = pw[k];
            const float s0 = wt.x * blo(u00[k].x) + wt.y * blo(u01[k].x) + wt.z * blo(u10[k].x) + wt.w * blo(u11[k].x);
            const float s1 = wt.x * bhi(u00[k].x) + wt.y * bhi(u01[k].x) + wt.z * bhi(u10[k].x) + wt.w * bhi(u11[k].x);
            const float s2 = wt.x * blo(u00[k].y) + wt.y * blo(u01[k].y) + wt.z * blo(u10[k].y) + wt.w * blo(u11[k].y);
            const float s3 = wt.x * bhi(u00[k].y) + wt.y * bhi(u01[k].y) + wt.z * bhi(u10[k].y) + wt.w * bhi(u11[k].y);
            *reinterpret_cast<uint2*>(reinterpret_cast<char*>(imcol) + wbase + k * 128) =
                make_uint2(cvtpk(s0, s1), cvtpk(s2, s3));
        }
    }
    __syncthreads();

    // ---- Phase E: GEMM2, wave = 16 o-rows x 32 px (2 n-tiles) ----
    f32x4 acc[2] = {{0.f,0.f,0.f,0.f},{0.f,0.f,0.f,0.f}};
    const unsigned short* wrow = wA + (size_t)(wv * 16 + l15) * CK;
#pragma unroll 3
    for (int ks = 0; ks < 18; ++ks) {
        const bf16x8 af = *reinterpret_cast<const bf16x8*>(wrow + ks * 32 + q * 8);
#pragma unroll
        for (int nt = 0; nt < 2; ++nt) {
            const int row = nt * 16 + l15;
            int byte = row * (CK * 2) + ks * 64 + q * 16;
            byte ^= (row & 7) << 4;
            const bf16x8 bfv = *reinterpret_cast<const bf16x8*>(
                reinterpret_cast<const char*>(imcol) + byte);
            acc[nt] = __builtin_amdgcn_mfma_f32_16x16x32_bf16(af, bfv, acc[nt], 0, 0, 0);
        }
    }

    // ---- Store ----
    const int o0 = wv * 16 + q * 4;
#pragma unroll
    for (int nt = 0; nt < 2; ++nt) {
        const int pixn = pix0 + nt * 16 + l15;
        const int hw   = pixn - bb * HW;
#pragma unroll
        for (int r = 0; r < 4; ++r)
            out[((size_t)bb * COUT + o0 + r) * HW + hw] = acc[nt][r];
    }
}

// ---------------------------------------------------------------------------
extern "C" void kernel_launch(void* const* d_in, const int* in_sizes, int n_in,
                              void* d_out, int out_size, void* d_ws, size_t ws_size,
                              hipStream_t stream) {
    const float* x     = (const float*)d_in[0];
    const float* w_off = (const float*)d_in[1];
    const float* b_off = (const float*)d_in[2];
    const float* w_msk = (const float*)d_in[3];
    const float* b_msk = (const float*)d_in[4];
    const float* w_def = (const float*)d_in[5];
    float* out = (float*)d_out;

    unsigned short* xpadT = (unsigned short*)d_ws;            // B*Hp*Wp*C bf16
    float* biasv = (float*)(xpadT + (size_t)B * Hp * Wp * C); // 32 floats
    unsigned short* wA   = (unsigned short*)(biasv + 32);     // 64*576 bf16
    unsigned short* womA = wA + (size_t)COUT * CK;            // 32*576 bf16

    k_prep<<<PAD_BLKS + BOR_BLKS + WA_BLKS + WOM_BLKS, 256, 0, stream>>>(
        x, xpadT, w_def, wA, w_off, w_msk, b_off, b_msk, womA, biasv);
    k_fused<<<NPIX / CPB, 256, 0, stream>>>(xpadT, womA, wA, biasv, out);
}